// Round 2
// baseline (756.538 us; speedup 1.0000x reference)
//
#include <hip/hip_runtime.h>

// Problem dims (hardcoded)
#define Tq 2048
#define Cq 2048
#define Hn 16
#define HSz 128
#define Bq 4
#define SCALE_QK 0.08838834764831845f  // 1/sqrt(128)

typedef __bf16 bf16x8 __attribute__((ext_vector_type(8)));
typedef float f32x4 __attribute__((ext_vector_type(4)));
typedef unsigned short u16;
typedef u16 u16x4 __attribute__((ext_vector_type(4)));

__device__ __forceinline__ u16 f2bf(float f) {
  unsigned u = __builtin_bit_cast(unsigned, f);
  u += 0x7FFFu + ((u >> 16) & 1u);   // RNE
  return (u16)(u >> 16);
}

// alias-safe 16B fragment load (ds_read_b128 / global_load_dwordx4)
__device__ __forceinline__ bf16x8 ld_frag(const void* p) {
  bf16x8 v; __builtin_memcpy(&v, p, 16); return v;
}

// async global->LDS, 16B per lane; LDS dest is wave-uniform base (+lane*16 implicit)
__device__ __forceinline__ void glds16(void* lds, const void* g) {
  __builtin_amdgcn_global_load_lds(
      (const __attribute__((address_space(1))) void*)g,
      (__attribute__((address_space(3))) void*)lds, 16, 0, 0);
}

// ---------------- fp32 -> bf16 conversion ----------------
__global__ void cvt_bf16(const float* __restrict__ in, u16* __restrict__ out, int n) {
  int i = (blockIdx.x * 256 + threadIdx.x) * 4;
  if (i >= n) return;
  f32x4 v; __builtin_memcpy(&v, in + i, 16);
  u16x4 o;
  o[0] = f2bf(v[0]); o[1] = f2bf(v[1]); o[2] = f2bf(v[2]); o[3] = f2bf(v[3]);
  __builtin_memcpy(out + i, &o, 8);
}

// ---------------- m97-style 128x128 BT GEMM ----------------
// C[m][n] = sum_k A[m][k] * Bm[n][k]   (A: MxK row-major, Bm: NxK row-major)
// EPI 0: scatter to q/k [B,H,T,HS] bf16 and v^T [B,H,HS,T] bf16
// EPI 1: fp32 out + bias
template <int EPI>
__global__ __launch_bounds__(256)
void gemm_bt(const u16* __restrict__ A, const u16* __restrict__ Bm, int K,
             u16* __restrict__ qout, u16* __restrict__ kout, u16* __restrict__ vtout,
             float* __restrict__ fout, const float* __restrict__ bias) {
  __shared__ u16 As[128 * 32];
  __shared__ u16 Bs[128 * 32];
  const int tid = threadIdx.x;
  const int w = tid >> 6, l = tid & 63;
  const int wr = w >> 1, wc = w & 1;
  const int lr = l & 15, lg = l >> 4;
  const int m0 = blockIdx.y * 128, n0 = blockIdx.x * 128;

  f32x4 acc[4][4];
  const f32x4 fz = {0.f, 0.f, 0.f, 0.f};
#pragma unroll
  for (int i = 0; i < 4; ++i)
#pragma unroll
    for (int j = 0; j < 4; ++j) acc[i][j] = fz;

  const int rA = l >> 2;          // row within 1KB chunk (16 rows of 32 elems)
  const int colA = (l & 3) * 8;   // element col within row

  for (int k0 = 0; k0 < K; k0 += 32) {
    __syncthreads();  // previous tile's ds_reads done before overwrite
#pragma unroll
    for (int i = 0; i < 2; ++i) {
      int c = w * 2 + i;
      int r = c * 16 + rA;
      glds16(&As[c * 512], A + (size_t)(m0 + r) * K + k0 + colA);
      glds16(&Bs[c * 512], Bm + (size_t)(n0 + r) * K + k0 + colA);
    }
    asm volatile("s_waitcnt vmcnt(0)" ::: "memory");
    __syncthreads();

    bf16x8 af[4], bfr[4];
#pragma unroll
    for (int mi = 0; mi < 4; ++mi)
      af[mi] = ld_frag(&As[(wr * 64 + mi * 16 + lr) * 32 + lg * 8]);
#pragma unroll
    for (int nj = 0; nj < 4; ++nj)
      bfr[nj] = ld_frag(&Bs[(wc * 64 + nj * 16 + lr) * 32 + lg * 8]);
#pragma unroll
    for (int mi = 0; mi < 4; ++mi)
#pragma unroll
      for (int nj = 0; nj < 4; ++nj)
        acc[mi][nj] = __builtin_amdgcn_mfma_f32_16x16x32_bf16(af[mi], bfr[nj], acc[mi][nj], 0, 0, 0);
  }

  // C/D layout: col = lr (within 16-col frag), row = lg*4 + rr
  if constexpr (EPI == 0) {
#pragma unroll
    for (int mi = 0; mi < 4; ++mi) {
      const int trow = m0 + wr * 64 + mi * 16 + lg * 4;  // +rr
      const int bb = trow >> 11;                         // batch (T=2048)
      const int tt0 = trow & 2047;
#pragma unroll
      for (int nj = 0; nj < 4; ++nj) {
        const int d = n0 + wc * 64 + nj * 16 + lr;  // 0..6143
        const int part = d >> 11;
        const int dd = d & 2047;
        const int h = dd >> 7;
        const int hs = dd & 127;
        if (part == 2) {
          // v transposed: vt[((b*H+h)*HS + hs)*T + t], 4 consecutive t per lane
          u16x4 pk;
          pk[0] = f2bf(acc[mi][nj][0]);
          pk[1] = f2bf(acc[mi][nj][1]);
          pk[2] = f2bf(acc[mi][nj][2]);
          pk[3] = f2bf(acc[mi][nj][3]);
          size_t off = ((size_t)(bb * Hn + h) * HSz + hs) * Tq + tt0;
          __builtin_memcpy(&vtout[off], &pk, 8);
        } else {
          u16* dst = (part == 0) ? qout : kout;
#pragma unroll
          for (int rr = 0; rr < 4; ++rr) {
            size_t off = ((size_t)(bb * Hn + h) * Tq + (tt0 + rr)) * HSz + hs;
            dst[off] = f2bf(acc[mi][nj][rr]);
          }
        }
      }
    }
  } else {
#pragma unroll
    for (int mi = 0; mi < 4; ++mi) {
      const int trow = m0 + wr * 64 + mi * 16 + lg * 4;
#pragma unroll
      for (int nj = 0; nj < 4; ++nj) {
        const int d = n0 + wc * 64 + nj * 16 + lr;
        const float bv = bias[d];
#pragma unroll
        for (int rr = 0; rr < 4; ++rr)
          fout[(size_t)(trow + rr) * Cq + d] = acc[mi][nj][rr] + bv;
      }
    }
  }
}

// ---------------- flash attention (causal) ----------------
// grid: (T/128, B*H); 4 waves, wave w owns q rows [w*32, w*32+32)
// K tile [128][128] and V^T tile [128][128] in LDS, XOR-swizzled (T2, both-sides).
// P relayout via per-wave 32x32 swizzled LDS chunk per 32-wide kv slice.
#define KVB 128
__global__ __launch_bounds__(256, 2)
void attn_fwd(const u16* __restrict__ qb, const u16* __restrict__ kb,
              const u16* __restrict__ vtb, u16* __restrict__ ob) {
  __shared__ u16 Ks[KVB * HSz];   // 32 KB, rows=kv, cols=hs (swizzled)
  __shared__ u16 Vs[HSz * KVB];   // 32 KB, rows=d,  cols=kv (swizzled)
  __shared__ u16 Ps[4 * 32 * 32]; // 8 KB, per-wave 32x32 chunk (swizzled)

  const int tid = threadIdx.x;
  const int w = tid >> 6, l = tid & 63;
  const int lr = l & 15, lg = l >> 4;
  const int qt = blockIdx.x, bh = blockIdx.y;
  const int q0 = qt * 128;

  const u16* qp = qb + (size_t)bh * Tq * HSz;
  const u16* kp = kb + (size_t)bh * Tq * HSz;
  const u16* vp = vtb + (size_t)bh * HSz * Tq;

  // Q fragments in registers: rows w*32+mi*16+lr, k = kk*32 + lg*8 + j
  bf16x8 qf[2][4];
#pragma unroll
  for (int mi = 0; mi < 2; ++mi)
#pragma unroll
    for (int kk = 0; kk < 4; ++kk) {
      int row = q0 + w * 32 + mi * 16 + lr;
      qf[mi][kk] = ld_frag(qp + (size_t)row * HSz + kk * 32 + lg * 8);
    }

  const f32x4 fz = {0.f, 0.f, 0.f, 0.f};
  f32x4 o[2][8];
  float mrow[2][4], lrow[2][4];
#pragma unroll
  for (int mi = 0; mi < 2; ++mi) {
#pragma unroll
    for (int nj = 0; nj < 8; ++nj) o[mi][nj] = fz;
#pragma unroll
    for (int rr = 0; rr < 4; ++rr) { mrow[mi][rr] = -1e30f; lrow[mi][rr] = 0.f; }
  }

  const int nt = qt + 1;
  for (int t = 0; t < nt; ++t) {
    const int kv0 = t * KVB;
    __syncthreads();  // all waves done reading Ks/Vs before restage
#pragma unroll
    for (int i = 0; i < 8; ++i) {
      int c = w * 8 + i;
      int r = c * 4 + lg;                        // row within tile
      int cb = (lr * 16) ^ ((r & 7) << 4);       // pre-swizzled source column (bytes)
      glds16(&Ks[c * 512], kp + (size_t)(kv0 + r) * HSz + (cb >> 1));
      glds16(&Vs[c * 512], vp + (size_t)r * Tq + kv0 + (cb >> 1));
    }
    asm volatile("s_waitcnt vmcnt(0)" ::: "memory");
    __syncthreads();

    // S = Q K^T  (B-fragments = K rows, contiguous hs)
    f32x4 s[2][8];
#pragma unroll
    for (int mi = 0; mi < 2; ++mi)
#pragma unroll
      for (int nj = 0; nj < 8; ++nj) s[mi][nj] = fz;
#pragma unroll
    for (int kk = 0; kk < 4; ++kk) {
      bf16x8 kf[8];
#pragma unroll
      for (int nj = 0; nj < 8; ++nj) {
        int row = nj * 16 + lr;
        int cb = (kk * 64 + lg * 16) ^ ((row & 7) << 4);
        kf[nj] = ld_frag((const char*)Ks + row * 256 + cb);
      }
#pragma unroll
      for (int mi = 0; mi < 2; ++mi)
#pragma unroll
        for (int nj = 0; nj < 8; ++nj)
          s[mi][nj] = __builtin_amdgcn_mfma_f32_16x16x32_bf16(qf[mi][kk], kf[nj], s[mi][nj], 0, 0, 0);
    }

    // scale + causal mask + online softmax (rows = lg*4+rr, cols = lr)
    const bool diag = (t == qt);
#pragma unroll
    for (int mi = 0; mi < 2; ++mi) {
#pragma unroll
      for (int rr = 0; rr < 4; ++rr) {
        const int qrow = q0 + w * 32 + mi * 16 + lg * 4 + rr;
        float pm = -1e30f;
#pragma unroll
        for (int nj = 0; nj < 8; ++nj) {
          float v = s[mi][nj][rr] * SCALE_QK;
          if (diag && (kv0 + nj * 16 + lr) > qrow) v = -1e30f;
          s[mi][nj][rr] = v;
          pm = fmaxf(pm, v);
        }
        pm = fmaxf(pm, __shfl_xor(pm, 1));
        pm = fmaxf(pm, __shfl_xor(pm, 2));
        pm = fmaxf(pm, __shfl_xor(pm, 4));
        pm = fmaxf(pm, __shfl_xor(pm, 8));
        float mo = mrow[mi][rr];
        float mn = fmaxf(mo, pm);
        float corr = __expf(mo - mn);
        mrow[mi][rr] = mn;
        float rs = 0.f;
#pragma unroll
        for (int nj = 0; nj < 8; ++nj) {
          float p = __expf(s[mi][nj][rr] - mn);
          s[mi][nj][rr] = p;
          rs += p;
        }
        rs += __shfl_xor(rs, 1);
        rs += __shfl_xor(rs, 2);
        rs += __shfl_xor(rs, 4);
        rs += __shfl_xor(rs, 8);
        lrow[mi][rr] = lrow[mi][rr] * corr + rs;
#pragma unroll
        for (int nj = 0; nj < 8; ++nj) o[mi][nj][rr] *= corr;
      }
    }

    // PV: per 32-wide kv slice, relayout P via per-wave LDS chunk, then MFMA
    char* pw = (char*)Ps + w * 2048;
#pragma unroll
    for (int kk = 0; kk < 4; ++kk) {
#pragma unroll
      for (int mi = 0; mi < 2; ++mi)
#pragma unroll
        for (int jj = 0; jj < 2; ++jj) {
          int nj = kk * 2 + jj;
#pragma unroll
          for (int rr = 0; rr < 4; ++rr) {
            int prow = mi * 16 + lg * 4 + rr;       // local q row 0..31
            int pcb = (jj * 16 + lr) * 2;           // byte within 64B row
            *(u16*)(pw + ((prow * 64 + pcb) ^ ((prow & 7) << 4))) = f2bf(s[mi][nj][rr]);
          }
        }
      bf16x8 pa[2];
#pragma unroll
      for (int mi = 0; mi < 2; ++mi) {
        int prow = mi * 16 + lr;
        pa[mi] = ld_frag(pw + ((prow * 64 + lg * 16) ^ ((prow & 7) << 4)));
      }
#pragma unroll
      for (int nj = 0; nj < 8; ++nj) {
        int vrow = nj * 16 + lr;
        int cb = (kk * 64 + lg * 16) ^ ((vrow & 7) << 4);
        bf16x8 vf = ld_frag((const char*)Vs + vrow * 256 + cb);
#pragma unroll
        for (int mi = 0; mi < 2; ++mi)
          o[mi][nj] = __builtin_amdgcn_mfma_f32_16x16x32_bf16(pa[mi], vf, o[mi][nj], 0, 0, 0);
      }
    }
  }

  // epilogue: normalize and write attn output [B,T,C] bf16
  const int b = bh >> 4, h = bh & 15;
#pragma unroll
  for (int mi = 0; mi < 2; ++mi)
#pragma unroll
    for (int rr = 0; rr < 4; ++rr) {
      int trow = q0 + w * 32 + mi * 16 + lg * 4 + rr;
      float inv = 1.f / lrow[mi][rr];
#pragma unroll
      for (int nj = 0; nj < 8; ++nj) {
        int d = nj * 16 + lr;
        ob[((size_t)b * Tq + trow) * Cq + h * HSz + d] = f2bf(o[mi][nj][rr] * inv);
      }
    }
}

// ---------------- launch ----------------
extern "C" void kernel_launch(void* const* d_in, const int* in_sizes, int n_in,
                              void* d_out, int out_size, void* d_ws, size_t ws_size,
                              hipStream_t stream) {
  const float* x = (const float*)d_in[0];       // [4,2048,2048]
  const float* w_qkv = (const float*)d_in[1];   // [6144,2048]
  const float* w_proj = (const float*)d_in[2];  // [2048,2048]
  const float* b_proj = (const float*)d_in[3];  // [2048]
  float* out = (float*)d_out;

  char* ws = (char*)d_ws;
  u16* xb     = (u16*)(ws);                         // 32 MiB  x bf16 / later attn-out bf16
  u16* wqkvb  = (u16*)(ws + (size_t)33554432);      // 24 MiB
  u16* wprojb = (u16*)(ws + (size_t)58720256);      // 8 MiB
  u16* qbp    = (u16*)(ws + (size_t)67108864);      // 32 MiB [B,H,T,HS]
  u16* kbp    = (u16*)(ws + (size_t)100663296);     // 32 MiB [B,H,T,HS]
  u16* vtbp   = (u16*)(ws + (size_t)134217728);     // 32 MiB [B,H,HS,T]
  (void)in_sizes; (void)n_in; (void)out_size; (void)ws_size;

  cvt_bf16<<<16384, 256, 0, stream>>>(x, xb, 16777216);
  cvt_bf16<<<12288, 256, 0, stream>>>(w_qkv, wqkvb, 12582912);
  cvt_bf16<<<4096, 256, 0, stream>>>(w_proj, wprojb, 4194304);

  // QKV: M=8192, N=6144, K=2048
  gemm_bt<0><<<dim3(48, 64), 256, 0, stream>>>(xb, wqkvb, 2048, qbp, kbp, vtbp, nullptr, nullptr);

  // attention (attn output overwrites xb; x no longer needed)
  attn_fwd<<<dim3(16, 64), 256, 0, stream>>>(qbp, kbp, vtbp, xb);

  // proj: M=8192, N=2048, K=2048, fp32 out + bias
  gemm_bt<1><<<dim3(16, 64), 256, 0, stream>>>(xb, wprojb, 2048, nullptr, nullptr, nullptr, out, b_proj);
}

// Round 4
// 581.703 us; speedup vs baseline: 1.3006x; 1.3006x over previous
//
#include <hip/hip_runtime.h>

// Problem dims (hardcoded)
#define Tq 2048
#define Cq 2048
#define Hn 16
#define HSz 128
#define Bq 4
#define SCALE_QK 0.08838834764831845f  // 1/sqrt(128)

typedef __bf16 bf16x8 __attribute__((ext_vector_type(8)));
typedef float f32x4 __attribute__((ext_vector_type(4)));
typedef unsigned short u16;
typedef u16 u16x4 __attribute__((ext_vector_type(4)));

__device__ __forceinline__ u16 f2bf(float f) {
  unsigned u = __builtin_bit_cast(unsigned, f);
  u += 0x7FFFu + ((u >> 16) & 1u);   // RNE
  return (u16)(u >> 16);
}

// alias-safe 16B fragment load (ds_read_b128 / global_load_dwordx4)
__device__ __forceinline__ bf16x8 ld_frag(const void* p) {
  bf16x8 v; __builtin_memcpy(&v, p, 16); return v;
}

// async global->LDS, 16B per lane; LDS dest is wave-uniform base (+lane*16 implicit)
__device__ __forceinline__ void glds16(void* lds, const void* g) {
  __builtin_amdgcn_global_load_lds(
      (const __attribute__((address_space(1))) void*)g,
      (__attribute__((address_space(3))) void*)lds, 16, 0, 0);
}

// ---------------- fp32 -> bf16 conversion ----------------
__global__ void cvt_bf16(const float* __restrict__ in, u16* __restrict__ out, int n) {
  int i = (blockIdx.x * 256 + threadIdx.x) * 4;
  if (i >= n) return;
  f32x4 v; __builtin_memcpy(&v, in + i, 16);
  u16x4 o;
  o[0] = f2bf(v[0]); o[1] = f2bf(v[1]); o[2] = f2bf(v[2]); o[3] = f2bf(v[3]);
  __builtin_memcpy(out + i, &o, 8);
}

// ---------------- m97-style 128x128 BT GEMM (+XCD swizzle) ----------------
// C[m][n] = sum_k A[m][k] * Bm[n][k]   (A: MxK row-major, Bm: NxK row-major)
// EPI 0: scatter to q/k [B,H,T,HS] bf16 and v^T [B,H,HS,T] bf16
// EPI 1: fp32 out + bias
template <int EPI>
__global__ __launch_bounds__(256)
void gemm_bt(const u16* __restrict__ A, const u16* __restrict__ Bm, int K,
             u16* __restrict__ qout, u16* __restrict__ kout, u16* __restrict__ vtout,
             float* __restrict__ fout, const float* __restrict__ bias) {
  __shared__ u16 As[128 * 32];
  __shared__ u16 Bs[128 * 32];
  const int tid = threadIdx.x;
  const int w = tid >> 6, l = tid & 63;
  const int wr = w >> 1, wc = w & 1;
  const int lr = l & 15, lg = l >> 4;

  // bijective XCD swizzle (nwg % 8 == 0 for all our grids)
  const int nwg = gridDim.x * gridDim.y;
  int ow = blockIdx.y * gridDim.x + blockIdx.x;
  ow = (ow & 7) * (nwg >> 3) + (ow >> 3);
  const int bx = ow % gridDim.x, by = ow / gridDim.x;
  const int m0 = by * 128, n0 = bx * 128;

  f32x4 acc[4][4];
  const f32x4 fz = {0.f, 0.f, 0.f, 0.f};
#pragma unroll
  for (int i = 0; i < 4; ++i)
#pragma unroll
    for (int j = 0; j < 4; ++j) acc[i][j] = fz;

  const int rA = l >> 2;          // row within 1KB chunk (16 rows of 32 elems)
  const int colA = (l & 3) * 8;   // element col within row

  for (int k0 = 0; k0 < K; k0 += 32) {
    __syncthreads();  // previous tile's ds_reads done before overwrite
#pragma unroll
    for (int i = 0; i < 2; ++i) {
      int c = w * 2 + i;
      int r = c * 16 + rA;
      glds16(&As[c * 512], A + (size_t)(m0 + r) * K + k0 + colA);
      glds16(&Bs[c * 512], Bm + (size_t)(n0 + r) * K + k0 + colA);
    }
    asm volatile("s_waitcnt vmcnt(0)" ::: "memory");
    __syncthreads();

    bf16x8 af[4], bfr[4];
#pragma unroll
    for (int mi = 0; mi < 4; ++mi)
      af[mi] = ld_frag(&As[(wr * 64 + mi * 16 + lr) * 32 + lg * 8]);
#pragma unroll
    for (int nj = 0; nj < 4; ++nj)
      bfr[nj] = ld_frag(&Bs[(wc * 64 + nj * 16 + lr) * 32 + lg * 8]);
#pragma unroll
    for (int mi = 0; mi < 4; ++mi)
#pragma unroll
      for (int nj = 0; nj < 4; ++nj)
        acc[mi][nj] = __builtin_amdgcn_mfma_f32_16x16x32_bf16(af[mi], bfr[nj], acc[mi][nj], 0, 0, 0);
  }

  // C/D layout: col = lr (within 16-col frag), row = lg*4 + rr
  if constexpr (EPI == 0) {
#pragma unroll
    for (int mi = 0; mi < 4; ++mi) {
      const int trow = m0 + wr * 64 + mi * 16 + lg * 4;  // +rr
      const int bb = trow >> 11;                         // batch (T=2048)
      const int tt0 = trow & 2047;
#pragma unroll
      for (int nj = 0; nj < 4; ++nj) {
        const int d = n0 + wc * 64 + nj * 16 + lr;  // 0..6143
        const int part = d >> 11;
        const int dd = d & 2047;
        const int h = dd >> 7;
        const int hs = dd & 127;
        if (part == 2) {
          // v transposed: vt[((b*H+h)*HS + hs)*T + t], 4 consecutive t per lane
          u16x4 pk;
          pk[0] = f2bf(acc[mi][nj][0]);
          pk[1] = f2bf(acc[mi][nj][1]);
          pk[2] = f2bf(acc[mi][nj][2]);
          pk[3] = f2bf(acc[mi][nj][3]);
          size_t off = ((size_t)(bb * Hn + h) * HSz + hs) * Tq + tt0;
          __builtin_memcpy(&vtout[off], &pk, 8);
        } else {
          u16* dst = (part == 0) ? qout : kout;
#pragma unroll
          for (int rr = 0; rr < 4; ++rr) {
            size_t off = ((size_t)(bb * Hn + h) * Tq + (tt0 + rr)) * HSz + hs;
            dst[off] = f2bf(acc[mi][nj][rr]);
          }
        }
      }
    }
  } else {
#pragma unroll
    for (int mi = 0; mi < 4; ++mi) {
      const int trow = m0 + wr * 64 + mi * 16 + lg * 4;
#pragma unroll
      for (int nj = 0; nj < 4; ++nj) {
        const int d = n0 + wc * 64 + nj * 16 + lr;
        const float bv = bias[d];
#pragma unroll
        for (int rr = 0; rr < 4; ++rr)
          fout[(size_t)(trow + rr) * Cq + d] = acc[mi][nj][rr] + bv;
      }
    }
  }
}

// ---------------- flash attention (causal, balanced + double-buffered) ----------------
// grid: (B*H, 8). Block (bh, j) processes q-tiles {j, 15-j} (128 rows each) ->
// every block does exactly 17 KV-128's of work. bh on x => same-head blocks
// co-locate on one XCD (L2 reuse of K/V).
// KV tiles of 64 staged via global_load_lds into double-buffered LDS with
// counted vmcnt(8) (T3/T4): next tile's loads fly under current tile's compute.
#define KVB 64
__global__ __launch_bounds__(256, 2)
void attn_fwd(const u16* __restrict__ qb, const u16* __restrict__ kb,
              const u16* __restrict__ vtb, u16* __restrict__ ob) {
  __shared__ u16 Ks[2 * KVB * HSz];   // 2 x 16KB, rows=kv (256B), swizzled
  __shared__ u16 Vs[2 * HSz * KVB];   // 2 x 16KB, rows=d (128B), swizzled
  __shared__ u16 Ps[4 * 32 * 32];     // 8KB, per-wave 32x32 chunk (swizzled)

  const int tid = threadIdx.x;
  const int w = tid >> 6, l = tid & 63;
  const int lr = l & 15, lg = l >> 4;
  const int bh = blockIdx.x, jj0 = blockIdx.y;
  const int b = bh >> 4, h = bh & 15;

  const u16* qp = qb + (size_t)bh * Tq * HSz;
  const u16* kp = kb + (size_t)bh * Tq * HSz;
  const u16* vp = vtb + (size_t)bh * HSz * Tq;

#pragma unroll 1
  for (int pass = 0; pass < 2; ++pass) {
    const int qt = pass ? (15 - jj0) : jj0;
    const int q0 = qt * 128;

    // Q fragments in registers: rows w*32+mi*16+lr, k = kk*32 + lg*8 + j
    bf16x8 qf[2][4];
#pragma unroll
    for (int mi = 0; mi < 2; ++mi)
#pragma unroll
      for (int kk = 0; kk < 4; ++kk) {
        int row = q0 + w * 32 + mi * 16 + lr;
        qf[mi][kk] = ld_frag(qp + (size_t)row * HSz + kk * 32 + lg * 8);
      }

    const f32x4 fz = {0.f, 0.f, 0.f, 0.f};
    f32x4 o[2][8];
    float mrow[2][4], lrow[2][4];
#pragma unroll
    for (int mi = 0; mi < 2; ++mi) {
#pragma unroll
      for (int nj = 0; nj < 8; ++nj) o[mi][nj] = fz;
#pragma unroll
      for (int rr = 0; rr < 4; ++rr) { mrow[mi][rr] = -1e30f; lrow[mi][rr] = 0.f; }
    }

    const int nt = 2 * (qt + 1);

    // stage(tile t -> buffer buf): 8 glds16/wave (4 K-chunks + 4 V-chunks)
    auto stage = [&](int t, int buf) {
      const int kv0 = t * KVB;
      u16* Kb = &Ks[buf * (KVB * HSz)];
      u16* Vb = &Vs[buf * (HSz * KVB)];
#pragma unroll
      for (int i = 0; i < 4; ++i) {
        int c = w * 4 + i;
        {  // K chunk: 4 rows x 256B
          int r = c * 4 + lg;
          int cb = (lr * 16) ^ ((r & 7) << 4);
          glds16(&Kb[c * 512], (const char*)(kp + (size_t)(kv0 + r) * HSz) + cb);
        }
        {  // V chunk: 8 rows x 128B
          int r = c * 8 + (l >> 3);
          int cb = ((l & 7) * 16) ^ ((r & 7) << 4);
          glds16(&Vb[c * 512], (const char*)(vp + (size_t)r * Tq + kv0) + cb);
        }
      }
    };

    stage(0, 0);
#pragma unroll 1
    for (int t = 0; t < nt; ++t) {
      const int buf = t & 1;
      if (t + 1 < nt) {
        stage(t + 1, buf ^ 1);
        asm volatile("s_waitcnt vmcnt(8)\ns_barrier" ::: "memory");  // tile t ready; t+1 in flight
      } else {
        asm volatile("s_waitcnt vmcnt(0)\ns_barrier" ::: "memory");
      }
      const u16* Ksb = &Ks[buf * (KVB * HSz)];
      const u16* Vsb = &Vs[buf * (HSz * KVB)];
      const int kv0 = t * KVB;

      // S = Q K^T  (B-fragments = K rows, contiguous hs)
      f32x4 s[2][4];
#pragma unroll
      for (int mi = 0; mi < 2; ++mi)
#pragma unroll
        for (int nj = 0; nj < 4; ++nj) s[mi][nj] = fz;
#pragma unroll
      for (int kk = 0; kk < 4; ++kk) {
        bf16x8 kf[4];
#pragma unroll
        for (int nj = 0; nj < 4; ++nj) {
          int row = nj * 16 + lr;
          int cb = (kk * 64 + lg * 16) ^ ((row & 7) << 4);
          kf[nj] = ld_frag((const char*)Ksb + row * 256 + cb);
        }
        __builtin_amdgcn_s_setprio(1);
#pragma unroll
        for (int mi = 0; mi < 2; ++mi)
#pragma unroll
          for (int nj = 0; nj < 4; ++nj)
            s[mi][nj] = __builtin_amdgcn_mfma_f32_16x16x32_bf16(qf[mi][kk], kf[nj], s[mi][nj], 0, 0, 0);
        __builtin_amdgcn_s_setprio(0);
      }

      // scale + causal mask + online softmax (rows = lg*4+rr, cols = lr)
      const bool diag = (t >= nt - 2);
      float corr[2][4];
      bool grew = false;
#pragma unroll
      for (int mi = 0; mi < 2; ++mi) {
#pragma unroll
        for (int rr = 0; rr < 4; ++rr) {
          const int qrow = q0 + w * 32 + mi * 16 + lg * 4 + rr;
          float pm = -1e30f;
#pragma unroll
          for (int nj = 0; nj < 4; ++nj) {
            float v = s[mi][nj][rr] * SCALE_QK;
            if (diag && (kv0 + nj * 16 + lr) > qrow) v = -1e30f;
            s[mi][nj][rr] = v;
            pm = fmaxf(pm, v);
          }
          pm = fmaxf(pm, __shfl_xor(pm, 1));
          pm = fmaxf(pm, __shfl_xor(pm, 2));
          pm = fmaxf(pm, __shfl_xor(pm, 4));
          pm = fmaxf(pm, __shfl_xor(pm, 8));
          float mo = mrow[mi][rr];
          float mn = fmaxf(mo, pm);
          corr[mi][rr] = __expf(mo - mn);
          grew |= (pm > mo);
          mrow[mi][rr] = mn;
          float rs = 0.f;
#pragma unroll
          for (int nj = 0; nj < 4; ++nj) {
            float p = __expf(s[mi][nj][rr] - mn);
            s[mi][nj][rr] = p;
            rs += p;
          }
          rs += __shfl_xor(rs, 1);
          rs += __shfl_xor(rs, 2);
          rs += __shfl_xor(rs, 4);
          rs += __shfl_xor(rs, 8);
          lrow[mi][rr] = lrow[mi][rr] * corr[mi][rr] + rs;
        }
      }
      if (__any(grew)) {  // T13: skip O-rescale when no row max grew
#pragma unroll
        for (int mi = 0; mi < 2; ++mi)
#pragma unroll
          for (int nj = 0; nj < 8; ++nj)
#pragma unroll
            for (int rr = 0; rr < 4; ++rr) o[mi][nj][rr] *= corr[mi][rr];
      }

      // PV: per 32-wide kv slice, relayout P via per-wave LDS chunk, then MFMA
      char* pw = (char*)Ps + w * 2048;
#pragma unroll
      for (int kk = 0; kk < 2; ++kk) {
#pragma unroll
        for (int mi = 0; mi < 2; ++mi)
#pragma unroll
          for (int jj = 0; jj < 2; ++jj) {
            int nj = kk * 2 + jj;
#pragma unroll
            for (int rr = 0; rr < 4; ++rr) {
              int prow = mi * 16 + lg * 4 + rr;       // local q row 0..31
              int pcb = (jj * 16 + lr) * 2;           // byte within 64B row
              *(u16*)(pw + ((prow * 64 + pcb) ^ ((prow & 7) << 4))) = f2bf(s[mi][nj][rr]);
            }
          }
        bf16x8 pa[2];
#pragma unroll
        for (int mi = 0; mi < 2; ++mi) {
          int prow = mi * 16 + lr;
          pa[mi] = ld_frag(pw + ((prow * 64 + lg * 16) ^ ((prow & 7) << 4)));
        }
        __builtin_amdgcn_s_setprio(1);
#pragma unroll
        for (int nj = 0; nj < 8; ++nj) {
          int vrow = nj * 16 + lr;
          int cb = (kk * 64 + lg * 16) ^ ((vrow & 7) << 4);
          bf16x8 vf = ld_frag((const char*)Vsb + vrow * 128 + cb);
#pragma unroll
          for (int mi = 0; mi < 2; ++mi)
            o[mi][nj] = __builtin_amdgcn_mfma_f32_16x16x32_bf16(pa[mi], vf, o[mi][nj], 0, 0, 0);
        }
        __builtin_amdgcn_s_setprio(0);
      }

      asm volatile("s_barrier" ::: "memory");  // all reads of buf done before restage
    }

    // epilogue: normalize and write attn output [B,T,C] bf16
#pragma unroll
    for (int mi = 0; mi < 2; ++mi)
#pragma unroll
      for (int rr = 0; rr < 4; ++rr) {
        int trow = q0 + w * 32 + mi * 16 + lg * 4 + rr;
        float inv = 1.f / lrow[mi][rr];
#pragma unroll
        for (int nj = 0; nj < 8; ++nj) {
          int d = nj * 16 + lr;
          ob[((size_t)b * Tq + trow) * Cq + h * HSz + d] = f2bf(o[mi][nj][rr] * inv);
        }
      }
  }
}

// ---------------- launch ----------------
extern "C" void kernel_launch(void* const* d_in, const int* in_sizes, int n_in,
                              void* d_out, int out_size, void* d_ws, size_t ws_size,
                              hipStream_t stream) {
  const float* x = (const float*)d_in[0];       // [4,2048,2048]
  const float* w_qkv = (const float*)d_in[1];   // [6144,2048]
  const float* w_proj = (const float*)d_in[2];  // [2048,2048]
  const float* b_proj = (const float*)d_in[3];  // [2048]
  float* out = (float*)d_out;

  char* ws = (char*)d_ws;
  u16* xb     = (u16*)(ws);                         // 32 MiB  x bf16 / later attn-out bf16
  u16* wqkvb  = (u16*)(ws + (size_t)33554432);      // 24 MiB
  u16* wprojb = (u16*)(ws + (size_t)58720256);      // 8 MiB
  u16* qbp    = (u16*)(ws + (size_t)67108864);      // 32 MiB [B,H,T,HS]
  u16* kbp    = (u16*)(ws + (size_t)100663296);     // 32 MiB [B,H,T,HS]
  u16* vtbp   = (u16*)(ws + (size_t)134217728);     // 32 MiB [B,H,HS,T]
  (void)in_sizes; (void)n_in; (void)out_size; (void)ws_size;

  cvt_bf16<<<16384, 256, 0, stream>>>(x, xb, 16777216);
  cvt_bf16<<<12288, 256, 0, stream>>>(w_qkv, wqkvb, 12582912);
  cvt_bf16<<<4096, 256, 0, stream>>>(w_proj, wprojb, 4194304);

  // QKV: M=8192, N=6144, K=2048
  gemm_bt<0><<<dim3(48, 64), 256, 0, stream>>>(xb, wqkvb, 2048, qbp, kbp, vtbp, nullptr, nullptr);

  // attention (attn output overwrites xb; x no longer needed)
  attn_fwd<<<dim3(64, 8), 256, 0, stream>>>(qbp, kbp, vtbp, xb);

  // proj: M=8192, N=2048, K=2048, fp32 out + bias
  gemm_bt<1><<<dim3(16, 64), 256, 0, stream>>>(xb, wprojb, 2048, nullptr, nullptr, nullptr, out, b_proj);
}

// Round 5
// 471.477 us; speedup vs baseline: 1.6046x; 1.2338x over previous
//
#include <hip/hip_runtime.h>

// Problem dims (hardcoded)
#define Tq 2048
#define Cq 2048
#define Hn 16
#define HSz 128
#define Bq 4
#define SCALE_QK 0.08838834764831845f  // 1/sqrt(128)

typedef __bf16 bf16x8 __attribute__((ext_vector_type(8)));
typedef float f32x4 __attribute__((ext_vector_type(4)));
typedef unsigned short u16;
typedef u16 u16x4 __attribute__((ext_vector_type(4)));

__device__ __forceinline__ u16 f2bf(float f) {
  unsigned u = __builtin_bit_cast(unsigned, f);
  u += 0x7FFFu + ((u >> 16) & 1u);   // RNE
  return (u16)(u >> 16);
}

__device__ __forceinline__ bf16x8 ld_frag(const void* p) {
  bf16x8 v; __builtin_memcpy(&v, p, 16); return v;
}

__device__ __forceinline__ void glds16(void* lds, const void* g) {
  __builtin_amdgcn_global_load_lds(
      (const __attribute__((address_space(1))) void*)g,
      (__attribute__((address_space(3))) void*)lds, 16, 0, 0);
}

// ---------------- fp32 -> bf16 conversion ----------------
__global__ void cvt_bf16(const float* __restrict__ in, u16* __restrict__ out, int n) {
  int i = (blockIdx.x * 256 + threadIdx.x) * 4;
  if (i >= n) return;
  f32x4 v; __builtin_memcpy(&v, in + i, 16);
  u16x4 o;
  o[0] = f2bf(v[0]); o[1] = f2bf(v[1]); o[2] = f2bf(v[2]); o[3] = f2bf(v[3]);
  __builtin_memcpy(out + i, &o, 8);
}

// ---------------- 256x256 8-phase BT GEMM (T2+T3+T4+T5, XCD swizzle) ----------------
// C[m][n] = sum_k A[m][k] * Bm[n][k]. 512 threads = 8 waves (2M x 4N), BK=64,
// 2 K-tiles per iteration (slot0/slot1), 8 phases/iter, one half-tile staged
// per phase, vmcnt(6) fences only at phases 4 and 8.
// LDS A slot: region[mh] rows r -> global row ((r>>6)&1)*128 + mh*64 + (r&63)
// LDS B slot: region[nh] rows r -> global col ((r>>5)&3)*64  + nh*32 + (r&31)
// XOR swizzle: byte ^= (row&7)<<4 applied on both staging source and ds_read.

#define LDA(s, mh) do { \
  _Pragma("unroll") for (int mi2_ = 0; mi2_ < 4; ++mi2_) \
  _Pragma("unroll") for (int kk_ = 0; kk_ < 2; ++kk_) { \
    const int row_ = (mh)*128 + wm*64 + mi2_*16 + lr; \
    af[mi2_*2+kk_] = ld_frag(AsB + (s)*32768 + row_*128 + ((kk_*64 + lg*16) ^ swz)); \
  } } while(0)

#define LDB(s, nh, BF) do { \
  _Pragma("unroll") for (int nf2_ = 0; nf2_ < 2; ++nf2_) \
  _Pragma("unroll") for (int kk_ = 0; kk_ < 2; ++kk_) { \
    const int row_ = (nh)*128 + wn*32 + nf2_*16 + lr; \
    BF[nf2_*2+kk_] = ld_frag(BsB + (s)*32768 + row_*128 + ((kk_*64 + lg*16) ^ swz)); \
  } } while(0)

#define QUAD(mh, nh, BF) do { \
  _Pragma("unroll") for (int mi2_ = 0; mi2_ < 4; ++mi2_) \
  _Pragma("unroll") for (int nf2_ = 0; nf2_ < 2; ++nf2_) \
  _Pragma("unroll") for (int kk_ = 0; kk_ < 2; ++kk_) \
    acc[(mh)*4+mi2_][(nh)*2+nf2_] = __builtin_amdgcn_mfma_f32_16x16x32_bf16( \
        af[mi2_*2+kk_], BF[nf2_*2+kk_], acc[(mh)*4+mi2_][(nh)*2+nf2_], 0, 0, 0); \
  } while(0)

#define STAGE_A(s, mh, k0) do { \
    u16* dst_ = Asu + (s)*16384 + (mh)*8192; \
    const u16* sp_ = A + (size_t)(m0 + (mh)*64 + arow0) * K + (k0) + srcE; \
    glds16(dst_ + w*512, sp_); \
    glds16(dst_ + (8+w)*512, sp_ + (size_t)128 * K); \
  } while(0)

#define STAGE_B(s, nh, k0) do { \
    u16* dst_ = Bsu + (s)*16384 + (nh)*8192; \
    glds16(dst_ + w*512,     Bm + (size_t)(n0 + (nh)*32 + brow0) * K + (k0) + srcE); \
    glds16(dst_ + (8+w)*512, Bm + (size_t)(n0 + (nh)*32 + brow1) * K + (k0) + srcE); \
  } while(0)

#define SYNC_MFMA(QPART) do { \
    asm volatile("s_barrier" ::: "memory"); \
    asm volatile("s_waitcnt lgkmcnt(0)" ::: "memory"); \
    __builtin_amdgcn_sched_barrier(0); \
    __builtin_amdgcn_s_setprio(1); \
    QPART; \
    __builtin_amdgcn_s_setprio(0); \
    asm volatile("s_barrier" ::: "memory"); \
  } while(0)

template <int EPI>
__global__ __launch_bounds__(512)
void gemm256(const u16* __restrict__ A, const u16* __restrict__ Bm, int K,
             u16* __restrict__ qout, u16* __restrict__ kout, u16* __restrict__ vtout,
             float* __restrict__ fout, const float* __restrict__ bias) {
  __shared__ u16 As2[2 * 256 * 64];   // 64 KB
  __shared__ u16 Bs2[2 * 256 * 64];   // 64 KB
  const int tid = threadIdx.x;
  const int w = tid >> 6, l = tid & 63;
  const int wm = w >> 2, wn = w & 3;
  const int lr = l & 15, lg = l >> 4;
  const int swz = (lr & 7) << 4;

  // bijective XCD swizzle (nwg % 8 == 0 for all our grids)
  const int nwg = gridDim.x * gridDim.y;
  int ow = blockIdx.y * gridDim.x + blockIdx.x;
  ow = (ow & 7) * (nwg >> 3) + (ow >> 3);
  const int bx = ow % gridDim.x, by = ow / gridDim.x;
  const int m0 = by * 256, n0 = bx * 256;

  // staging precompute (chunk c = issue*8 + w; lane covers row c*8+(l>>3), bytes (l&7)*16)
  const int r0 = w * 8 + (l >> 3);                  // issue-0 region row (0..63)
  const int arow0 = r0;                             // A: issue-1 row = arow0+128 (same inner)
  const int brow0 = (r0 >> 5) * 64 + (r0 & 31);
  const int brow1 = (((r0 + 64) >> 5) & 3) * 64 + (r0 & 31);
  const int srcE = ((l & 7) ^ (l >> 3)) << 3;       // pre-swizzled source element col

  u16* Asu = As2; u16* Bsu = Bs2;
  const char* AsB = (const char*)As2;
  const char* BsB = (const char*)Bs2;

  f32x4 acc[8][4];
  const f32x4 fz = {0.f, 0.f, 0.f, 0.f};
#pragma unroll
  for (int i = 0; i < 8; ++i)
#pragma unroll
    for (int j = 0; j < 4; ++j) acc[i][j] = fz;

  bf16x8 af[8], bf0[4], bf1[4];

  // prologue: stage h0..h6 of pair 0 (7 half-tiles), h7 staged at P1 of iter 0
  STAGE_A(0, 0, 0);  STAGE_B(0, 0, 0);  STAGE_B(0, 1, 0);  STAGE_A(0, 1, 0);
  STAGE_A(1, 0, 64); STAGE_B(1, 0, 64); STAGE_B(1, 1, 64);
  asm volatile("s_waitcnt vmcnt(6)" ::: "memory");   // h0..h3 landed
  asm volatile("s_barrier" ::: "memory");

  const int NP = K >> 7;   // pairs of K-tiles
#pragma unroll 1
  for (int t = 0; t < NP; ++t) {
    const bool lastp = (t == NP - 1);
    const int kA = (t + 1) << 7;   // pair t+1 k-base

    // P1: ds-read A mh0 + B nh0 (slot0); stage h7 of pair t (A slot1 mh1)
    LDA(0, 0); LDB(0, 0, bf0);
    STAGE_A(1, 1, (t << 7) + 64);
    SYNC_MFMA(QUAD(0, 0, bf0));
    // P2: ds-read B nh1; stage h0' (A slot0 mh0)
    LDB(0, 1, bf1);
    if (!lastp) STAGE_A(0, 0, kA);
    SYNC_MFMA(QUAD(0, 1, bf1));
    // P3: ds-read A mh1; stage h1' (B slot0 nh0)
    LDA(0, 1);
    if (!lastp) STAGE_B(0, 0, kA);
    SYNC_MFMA(QUAD(1, 1, bf1));
    // P4: stage h2' (B slot0 nh1); counted fence
    if (!lastp) { STAGE_B(0, 1, kA); asm volatile("s_waitcnt vmcnt(6)" ::: "memory"); }
    else        {                    asm volatile("s_waitcnt vmcnt(0)" ::: "memory"); }
    SYNC_MFMA(QUAD(1, 0, bf0));

    // P5: slot1: ds-read A mh0 + B nh0; stage h3' (A slot0 mh1)
    LDA(1, 0); LDB(1, 0, bf0);
    if (!lastp) STAGE_A(0, 1, kA);
    SYNC_MFMA(QUAD(0, 0, bf0));
    // P6: ds-read B nh1; stage h4' (A slot1 mh0)
    LDB(1, 1, bf1);
    if (!lastp) STAGE_A(1, 0, kA + 64);
    SYNC_MFMA(QUAD(0, 1, bf1));
    // P7: ds-read A mh1; stage h5' (B slot1 nh0)
    LDA(1, 1);
    if (!lastp) STAGE_B(1, 0, kA + 64);
    SYNC_MFMA(QUAD(1, 1, bf1));
    // P8: stage h6' (B slot1 nh1); counted fence
    if (!lastp) { STAGE_B(1, 1, kA + 64); asm volatile("s_waitcnt vmcnt(6)" ::: "memory"); }
    else        {                         asm volatile("s_waitcnt vmcnt(0)" ::: "memory"); }
    SYNC_MFMA(QUAD(1, 0, bf0));
  }

  // epilogue. C/D layout: col = lr, row = lg*4 + rr
  if constexpr (EPI == 0) {
#pragma unroll
    for (int mi = 0; mi < 8; ++mi) {
      const int trow = m0 + wm * 128 + mi * 16 + lg * 4;  // +rr
      const int bb = trow >> 11, tt0 = trow & 2047;
#pragma unroll
      for (int nf = 0; nf < 4; ++nf) {
        const int d = n0 + wn * 64 + nf * 16 + lr;  // 0..6143
        const int part = d >> 11;
        const int dd = d & 2047;
        const int hh = dd >> 7, hs = dd & 127;
        if (part == 2) {
          u16x4 pk;
          pk[0] = f2bf(acc[mi][nf][0]); pk[1] = f2bf(acc[mi][nf][1]);
          pk[2] = f2bf(acc[mi][nf][2]); pk[3] = f2bf(acc[mi][nf][3]);
          size_t off = ((size_t)(bb * Hn + hh) * HSz + hs) * Tq + tt0;
          __builtin_memcpy(&vtout[off], &pk, 8);
        } else {
          u16* dst = (part == 0) ? qout : kout;
#pragma unroll
          for (int rr = 0; rr < 4; ++rr) {
            size_t off = ((size_t)(bb * Hn + hh) * Tq + (tt0 + rr)) * HSz + hs;
            dst[off] = f2bf(acc[mi][nf][rr]);
          }
        }
      }
    }
  } else {
#pragma unroll
    for (int mi = 0; mi < 8; ++mi) {
      const int trow = m0 + wm * 128 + mi * 16 + lg * 4;
#pragma unroll
      for (int nf = 0; nf < 4; ++nf) {
        const int d = n0 + wn * 64 + nf * 16 + lr;
        const float bv = bias[d];
#pragma unroll
        for (int rr = 0; rr < 4; ++rr)
          fout[(size_t)(trow + rr) * Cq + d] = acc[mi][nf][rr] + bv;
      }
    }
  }
}

// ---------------- flash attention (causal, balanced + double-buffered) ----------------
#define KVB 64
__global__ __launch_bounds__(256, 2)
void attn_fwd(const u16* __restrict__ qb, const u16* __restrict__ kb,
              const u16* __restrict__ vtb, u16* __restrict__ ob) {
  __shared__ u16 Ks[2 * KVB * HSz];   // 2 x 16KB, rows=kv (256B), swizzled
  __shared__ u16 Vs[2 * HSz * KVB];   // 2 x 16KB, rows=d (128B), swizzled
  __shared__ u16 Ps[4 * 32 * 32];     // 8KB, per-wave 32x32 chunk (swizzled)

  const int tid = threadIdx.x;
  const int w = tid >> 6, l = tid & 63;
  const int lr = l & 15, lg = l >> 4;
  const int bh = blockIdx.x, jj0 = blockIdx.y;
  const int b = bh >> 4, h = bh & 15;

  const u16* qp = qb + (size_t)bh * Tq * HSz;
  const u16* kp = kb + (size_t)bh * Tq * HSz;
  const u16* vp = vtb + (size_t)bh * HSz * Tq;

#pragma unroll 1
  for (int pass = 0; pass < 2; ++pass) {
    const int qt = pass ? (15 - jj0) : jj0;
    const int q0 = qt * 128;

    bf16x8 qf[2][4];
#pragma unroll
    for (int mi = 0; mi < 2; ++mi)
#pragma unroll
      for (int kk = 0; kk < 4; ++kk) {
        int row = q0 + w * 32 + mi * 16 + lr;
        qf[mi][kk] = ld_frag(qp + (size_t)row * HSz + kk * 32 + lg * 8);
      }

    const f32x4 fz = {0.f, 0.f, 0.f, 0.f};
    f32x4 o[2][8];
    float mrow[2][4], lrow[2][4];
#pragma unroll
    for (int mi = 0; mi < 2; ++mi) {
#pragma unroll
      for (int nj = 0; nj < 8; ++nj) o[mi][nj] = fz;
#pragma unroll
      for (int rr = 0; rr < 4; ++rr) { mrow[mi][rr] = -1e30f; lrow[mi][rr] = 0.f; }
    }

    const int nt = 2 * (qt + 1);

    auto stage = [&](int t, int buf) {
      const int kv0 = t * KVB;
      u16* Kb = &Ks[buf * (KVB * HSz)];
      u16* Vb = &Vs[buf * (HSz * KVB)];
#pragma unroll
      for (int i = 0; i < 4; ++i) {
        int c = w * 4 + i;
        {  // K chunk: 4 rows x 256B
          int r = c * 4 + lg;
          int cb = (lr * 16) ^ ((r & 7) << 4);
          glds16(&Kb[c * 512], (const char*)(kp + (size_t)(kv0 + r) * HSz) + cb);
        }
        {  // V chunk: 8 rows x 128B
          int r = c * 8 + (l >> 3);
          int cb = ((l & 7) * 16) ^ ((r & 7) << 4);
          glds16(&Vb[c * 512], (const char*)(vp + (size_t)r * Tq + kv0) + cb);
        }
      }
    };

    stage(0, 0);
#pragma unroll 1
    for (int t = 0; t < nt; ++t) {
      const int buf = t & 1;
      if (t + 1 < nt) {
        stage(t + 1, buf ^ 1);
        asm volatile("s_waitcnt vmcnt(8)\ns_barrier" ::: "memory");
      } else {
        asm volatile("s_waitcnt vmcnt(0)\ns_barrier" ::: "memory");
      }
      const u16* Ksb = &Ks[buf * (KVB * HSz)];
      const u16* Vsb = &Vs[buf * (HSz * KVB)];
      const int kv0 = t * KVB;

      f32x4 s[2][4];
#pragma unroll
      for (int mi = 0; mi < 2; ++mi)
#pragma unroll
        for (int nj = 0; nj < 4; ++nj) s[mi][nj] = fz;
#pragma unroll
      for (int kk = 0; kk < 4; ++kk) {
        bf16x8 kf[4];
#pragma unroll
        for (int nj = 0; nj < 4; ++nj) {
          int row = nj * 16 + lr;
          int cb = (kk * 64 + lg * 16) ^ ((row & 7) << 4);
          kf[nj] = ld_frag((const char*)Ksb + row * 256 + cb);
        }
        __builtin_amdgcn_s_setprio(1);
#pragma unroll
        for (int mi = 0; mi < 2; ++mi)
#pragma unroll
          for (int nj = 0; nj < 4; ++nj)
            s[mi][nj] = __builtin_amdgcn_mfma_f32_16x16x32_bf16(qf[mi][kk], kf[nj], s[mi][nj], 0, 0, 0);
        __builtin_amdgcn_s_setprio(0);
      }

      const bool diag = (t >= nt - 2);
      float corr[2][4];
      bool grew = false;
#pragma unroll
      for (int mi = 0; mi < 2; ++mi) {
#pragma unroll
        for (int rr = 0; rr < 4; ++rr) {
          const int qrow = q0 + w * 32 + mi * 16 + lg * 4 + rr;
          float pm = -1e30f;
#pragma unroll
          for (int nj = 0; nj < 4; ++nj) {
            float v = s[mi][nj][rr] * SCALE_QK;
            if (diag && (kv0 + nj * 16 + lr) > qrow) v = -1e30f;
            s[mi][nj][rr] = v;
            pm = fmaxf(pm, v);
          }
          pm = fmaxf(pm, __shfl_xor(pm, 1));
          pm = fmaxf(pm, __shfl_xor(pm, 2));
          pm = fmaxf(pm, __shfl_xor(pm, 4));
          pm = fmaxf(pm, __shfl_xor(pm, 8));
          float mo = mrow[mi][rr];
          float mn = fmaxf(mo, pm);
          corr[mi][rr] = __expf(mo - mn);
          grew |= (pm > mo);
          mrow[mi][rr] = mn;
          float rs = 0.f;
#pragma unroll
          for (int nj = 0; nj < 4; ++nj) {
            float p = __expf(s[mi][nj][rr] - mn);
            s[mi][nj][rr] = p;
            rs += p;
          }
          rs += __shfl_xor(rs, 1);
          rs += __shfl_xor(rs, 2);
          rs += __shfl_xor(rs, 4);
          rs += __shfl_xor(rs, 8);
          lrow[mi][rr] = lrow[mi][rr] * corr[mi][rr] + rs;
        }
      }
      if (__any(grew)) {
#pragma unroll
        for (int mi = 0; mi < 2; ++mi)
#pragma unroll
          for (int nj = 0; nj < 8; ++nj)
#pragma unroll
            for (int rr = 0; rr < 4; ++rr) o[mi][nj][rr] *= corr[mi][rr];
      }

      char* pw = (char*)Ps + w * 2048;
#pragma unroll
      for (int kk = 0; kk < 2; ++kk) {
#pragma unroll
        for (int mi = 0; mi < 2; ++mi)
#pragma unroll
          for (int jj = 0; jj < 2; ++jj) {
            int nj = kk * 2 + jj;
#pragma unroll
            for (int rr = 0; rr < 4; ++rr) {
              int prow = mi * 16 + lg * 4 + rr;
              int pcb = (jj * 16 + lr) * 2;
              *(u16*)(pw + ((prow * 64 + pcb) ^ ((prow & 7) << 4))) = f2bf(s[mi][nj][rr]);
            }
          }
        bf16x8 pa[2];
#pragma unroll
        for (int mi = 0; mi < 2; ++mi) {
          int prow = mi * 16 + lr;
          pa[mi] = ld_frag(pw + ((prow * 64 + lg * 16) ^ ((prow & 7) << 4)));
        }
        __builtin_amdgcn_s_setprio(1);
#pragma unroll
        for (int nj = 0; nj < 8; ++nj) {
          int vrow = nj * 16 + lr;
          int cb = (kk * 64 + lg * 16) ^ ((vrow & 7) << 4);
          bf16x8 vf = ld_frag((const char*)Vsb + vrow * 128 + cb);
#pragma unroll
          for (int mi = 0; mi < 2; ++mi)
            o[mi][nj] = __builtin_amdgcn_mfma_f32_16x16x32_bf16(pa[mi], vf, o[mi][nj], 0, 0, 0);
        }
        __builtin_amdgcn_s_setprio(0);
      }

      asm volatile("s_barrier" ::: "memory");
    }

#pragma unroll
    for (int mi = 0; mi < 2; ++mi)
#pragma unroll
      for (int rr = 0; rr < 4; ++rr) {
        int trow = q0 + w * 32 + mi * 16 + lg * 4 + rr;
        float inv = 1.f / lrow[mi][rr];
#pragma unroll
        for (int nj = 0; nj < 8; ++nj) {
          int d = nj * 16 + lr;
          ob[((size_t)b * Tq + trow) * Cq + h * HSz + d] = f2bf(o[mi][nj][rr] * inv);
        }
      }
  }
}

// ---------------- launch ----------------
extern "C" void kernel_launch(void* const* d_in, const int* in_sizes, int n_in,
                              void* d_out, int out_size, void* d_ws, size_t ws_size,
                              hipStream_t stream) {
  const float* x = (const float*)d_in[0];       // [4,2048,2048]
  const float* w_qkv = (const float*)d_in[1];   // [6144,2048]
  const float* w_proj = (const float*)d_in[2];  // [2048,2048]
  const float* b_proj = (const float*)d_in[3];  // [2048]
  float* out = (float*)d_out;

  char* ws = (char*)d_ws;
  u16* xb     = (u16*)(ws);                         // 32 MiB  x bf16 / later attn-out bf16
  u16* wqkvb  = (u16*)(ws + (size_t)33554432);      // 24 MiB
  u16* wprojb = (u16*)(ws + (size_t)58720256);      // 8 MiB
  u16* qbp    = (u16*)(ws + (size_t)67108864);      // 32 MiB [B,H,T,HS]
  u16* kbp    = (u16*)(ws + (size_t)100663296);     // 32 MiB [B,H,T,HS]
  u16* vtbp   = (u16*)(ws + (size_t)134217728);     // 32 MiB [B,H,HS,T]
  (void)in_sizes; (void)n_in; (void)out_size; (void)ws_size;

  cvt_bf16<<<16384, 256, 0, stream>>>(x, xb, 16777216);
  cvt_bf16<<<12288, 256, 0, stream>>>(w_qkv, wqkvb, 12582912);
  cvt_bf16<<<4096, 256, 0, stream>>>(w_proj, wprojb, 4194304);

  // QKV: M=8192, N=6144, K=2048  (grid 24x32 = 768 blocks)
  gemm256<0><<<dim3(24, 32), 512, 0, stream>>>(xb, wqkvb, 2048, qbp, kbp, vtbp, nullptr, nullptr);

  // attention (attn output overwrites xb; x no longer needed)
  attn_fwd<<<dim3(64, 8), 256, 0, stream>>>(qbp, kbp, vtbp, xb);

  // proj: M=8192, N=2048, K=2048, fp32 out + bias (grid 8x32 = 256 blocks)
  gemm256<1><<<dim3(8, 32), 512, 0, stream>>>(xb, wprojb, 2048, nullptr, nullptr, nullptr, out, b_proj);
}

// Round 6
// 470.041 us; speedup vs baseline: 1.6095x; 1.0031x over previous
//
#include <hip/hip_runtime.h>

// Problem dims (hardcoded)
#define Tq 2048
#define Cq 2048
#define Hn 16
#define HSz 128
#define Bq 4
#define SCALE_QK 0.08838834764831845f  // 1/sqrt(128)

typedef __bf16 bf16x8 __attribute__((ext_vector_type(8)));
typedef float f32x4 __attribute__((ext_vector_type(4)));
typedef unsigned short u16;
typedef u16 u16x4 __attribute__((ext_vector_type(4)));

__device__ __forceinline__ u16 f2bf(float f) {
  unsigned u = __builtin_bit_cast(unsigned, f);
  u += 0x7FFFu + ((u >> 16) & 1u);   // RNE
  return (u16)(u >> 16);
}

__device__ __forceinline__ bf16x8 ld_frag(const void* p) {
  bf16x8 v; __builtin_memcpy(&v, p, 16); return v;
}

__device__ __forceinline__ void glds16(void* lds, const void* g) {
  __builtin_amdgcn_global_load_lds(
      (const __attribute__((address_space(1))) void*)g,
      (__attribute__((address_space(3))) void*)lds, 16, 0, 0);
}

// ---------------- fp32 -> bf16 conversion ----------------
__global__ void cvt_bf16(const float* __restrict__ in, u16* __restrict__ out, int n) {
  int i = (blockIdx.x * 256 + threadIdx.x) * 4;
  if (i >= n) return;
  f32x4 v; __builtin_memcpy(&v, in + i, 16);
  u16x4 o;
  o[0] = f2bf(v[0]); o[1] = f2bf(v[1]); o[2] = f2bf(v[2]); o[3] = f2bf(v[3]);
  __builtin_memcpy(out + i, &o, 8);
}

// ---------------- 256x256 8-phase BT GEMM (T2+T3+T4+T5, XCD swizzle) ----------------
// C[m][n] = sum_k A[m][k] * Bm[n][k]. 512 threads = 8 waves (2M x 4N), BK=64,
// 2 K-tiles per iteration (slot0/slot1), 8 phases/iter, one half-tile staged
// per phase, vmcnt(6) fences only at phases 4 and 8.
// This round: no explicit lgkmcnt(0)/sched_barrier in the phase sync — the
// compiler emits counted lgkmcnt(N) per dependent MFMA, pipelining the drain.
// Correctness: every ds_read is consumed by a MFMA before bar2, so all reads
// retire before any wave passes bar2 -> staging WAR still barrier-protected.

#define LDA(s, mh) do { \
  _Pragma("unroll") for (int mi2_ = 0; mi2_ < 4; ++mi2_) \
  _Pragma("unroll") for (int kk_ = 0; kk_ < 2; ++kk_) { \
    const int row_ = (mh)*128 + wm*64 + mi2_*16 + lr; \
    af[mi2_*2+kk_] = ld_frag(AsB + (s)*32768 + row_*128 + ((kk_*64 + lg*16) ^ swz)); \
  } } while(0)

#define LDB(s, nh, BF) do { \
  _Pragma("unroll") for (int nf2_ = 0; nf2_ < 2; ++nf2_) \
  _Pragma("unroll") for (int kk_ = 0; kk_ < 2; ++kk_) { \
    const int row_ = (nh)*128 + wn*32 + nf2_*16 + lr; \
    BF[nf2_*2+kk_] = ld_frag(BsB + (s)*32768 + row_*128 + ((kk_*64 + lg*16) ^ swz)); \
  } } while(0)

#define QUAD(mh, nh, BF) do { \
  _Pragma("unroll") for (int mi2_ = 0; mi2_ < 4; ++mi2_) \
  _Pragma("unroll") for (int nf2_ = 0; nf2_ < 2; ++nf2_) \
  _Pragma("unroll") for (int kk_ = 0; kk_ < 2; ++kk_) \
    acc[(mh)*4+mi2_][(nh)*2+nf2_] = __builtin_amdgcn_mfma_f32_16x16x32_bf16( \
        af[mi2_*2+kk_], BF[nf2_*2+kk_], acc[(mh)*4+mi2_][(nh)*2+nf2_], 0, 0, 0); \
  } while(0)

#define STAGE_A(s, mh, k0) do { \
    u16* dst_ = Asu + (s)*16384 + (mh)*8192; \
    const u16* sp_ = A + (size_t)(m0 + (mh)*64 + arow0) * K + (k0) + srcE; \
    glds16(dst_ + w*512, sp_); \
    glds16(dst_ + (8+w)*512, sp_ + (size_t)128 * K); \
  } while(0)

#define STAGE_B(s, nh, k0) do { \
    u16* dst_ = Bsu + (s)*16384 + (nh)*8192; \
    glds16(dst_ + w*512,     Bm + (size_t)(n0 + (nh)*32 + brow0) * K + (k0) + srcE); \
    glds16(dst_ + (8+w)*512, Bm + (size_t)(n0 + (nh)*32 + brow1) * K + (k0) + srcE); \
  } while(0)

#define SYNC_MFMA(QPART) do { \
    asm volatile("s_barrier" ::: "memory"); \
    __builtin_amdgcn_s_setprio(1); \
    QPART; \
    __builtin_amdgcn_s_setprio(0); \
    asm volatile("s_barrier" ::: "memory"); \
  } while(0)

template <int EPI>
__global__ __launch_bounds__(512)
void gemm256(const u16* __restrict__ A, const u16* __restrict__ Bm, int K,
             u16* __restrict__ qout, u16* __restrict__ kout, u16* __restrict__ vtout,
             float* __restrict__ fout, const float* __restrict__ bias) {
  __shared__ u16 As2[2 * 256 * 64];   // 64 KB
  __shared__ u16 Bs2[2 * 256 * 64];   // 64 KB
  const int tid = threadIdx.x;
  const int w = tid >> 6, l = tid & 63;
  const int wm = w >> 2, wn = w & 3;
  const int lr = l & 15, lg = l >> 4;
  const int swz = (lr & 7) << 4;

  // bijective XCD swizzle (nwg % 8 == 0 for all our grids)
  const int nwg = gridDim.x * gridDim.y;
  int ow = blockIdx.y * gridDim.x + blockIdx.x;
  ow = (ow & 7) * (nwg >> 3) + (ow >> 3);
  const int bx = ow % gridDim.x, by = ow / gridDim.x;
  const int m0 = by * 256, n0 = bx * 256;

  // staging precompute (chunk c = issue*8 + w; lane covers row c*8+(l>>3), bytes (l&7)*16)
  const int r0 = w * 8 + (l >> 3);                  // issue-0 region row (0..63)
  const int arow0 = r0;                             // A: issue-1 row = arow0+128 (same inner)
  const int brow0 = (r0 >> 5) * 64 + (r0 & 31);
  const int brow1 = (((r0 + 64) >> 5) & 3) * 64 + (r0 & 31);
  const int srcE = ((l & 7) ^ (l >> 3)) << 3;       // pre-swizzled source element col

  u16* Asu = As2; u16* Bsu = Bs2;
  const char* AsB = (const char*)As2;
  const char* BsB = (const char*)Bs2;

  f32x4 acc[8][4];
  const f32x4 fz = {0.f, 0.f, 0.f, 0.f};
#pragma unroll
  for (int i = 0; i < 8; ++i)
#pragma unroll
    for (int j = 0; j < 4; ++j) acc[i][j] = fz;

  bf16x8 af[8], bf0[4], bf1[4];

  // prologue: stage h0..h6 of pair 0 (7 half-tiles), h7 staged at P1 of iter 0
  STAGE_A(0, 0, 0);  STAGE_B(0, 0, 0);  STAGE_B(0, 1, 0);  STAGE_A(0, 1, 0);
  STAGE_A(1, 0, 64); STAGE_B(1, 0, 64); STAGE_B(1, 1, 64);
  asm volatile("s_waitcnt vmcnt(6)" ::: "memory");   // h0..h3 landed
  asm volatile("s_barrier" ::: "memory");

  const int NP = K >> 7;   // pairs of K-tiles
#pragma unroll 1
  for (int t = 0; t < NP; ++t) {
    const bool lastp = (t == NP - 1);
    const int kA = (t + 1) << 7;   // pair t+1 k-base

    // P1: ds-read A mh0 + B nh0 (slot0); stage h7 of pair t (A slot1 mh1)
    LDA(0, 0); LDB(0, 0, bf0);
    STAGE_A(1, 1, (t << 7) + 64);
    SYNC_MFMA(QUAD(0, 0, bf0));
    // P2: ds-read B nh1; stage h0' (A slot0 mh0)
    LDB(0, 1, bf1);
    if (!lastp) STAGE_A(0, 0, kA);
    SYNC_MFMA(QUAD(0, 1, bf1));
    // P3: ds-read A mh1; stage h1' (B slot0 nh0)
    LDA(0, 1);
    if (!lastp) STAGE_B(0, 0, kA);
    SYNC_MFMA(QUAD(1, 1, bf1));
    // P4: stage h2' (B slot0 nh1); counted fence
    if (!lastp) { STAGE_B(0, 1, kA); asm volatile("s_waitcnt vmcnt(6)" ::: "memory"); }
    else        {                    asm volatile("s_waitcnt vmcnt(0)" ::: "memory"); }
    SYNC_MFMA(QUAD(1, 0, bf0));

    // P5: slot1: ds-read A mh0 + B nh0; stage h3' (A slot0 mh1)
    LDA(1, 0); LDB(1, 0, bf0);
    if (!lastp) STAGE_A(0, 1, kA);
    SYNC_MFMA(QUAD(0, 0, bf0));
    // P6: ds-read B nh1; stage h4' (A slot1 mh0)
    LDB(1, 1, bf1);
    if (!lastp) STAGE_A(1, 0, kA + 64);
    SYNC_MFMA(QUAD(0, 1, bf1));
    // P7: ds-read A mh1; stage h5' (B slot1 nh0)
    LDA(1, 1);
    if (!lastp) STAGE_B(1, 0, kA + 64);
    SYNC_MFMA(QUAD(1, 1, bf1));
    // P8: stage h6' (B slot1 nh1); counted fence
    if (!lastp) { STAGE_B(1, 1, kA + 64); asm volatile("s_waitcnt vmcnt(6)" ::: "memory"); }
    else        {                         asm volatile("s_waitcnt vmcnt(0)" ::: "memory"); }
    SYNC_MFMA(QUAD(1, 0, bf0));
  }

  // epilogue. C/D layout: col = lr, row = lg*4 + rr
  if constexpr (EPI == 0) {
#pragma unroll
    for (int mi = 0; mi < 8; ++mi) {
      const int trow = m0 + wm * 128 + mi * 16 + lg * 4;  // +rr
      const int bb = trow >> 11, tt0 = trow & 2047;
#pragma unroll
      for (int nf = 0; nf < 4; ++nf) {
        const int d = n0 + wn * 64 + nf * 16 + lr;  // 0..6143
        const int part = d >> 11;
        const int dd = d & 2047;
        const int hh = dd >> 7, hs = dd & 127;
        if (part == 2) {
          u16x4 pk;
          pk[0] = f2bf(acc[mi][nf][0]); pk[1] = f2bf(acc[mi][nf][1]);
          pk[2] = f2bf(acc[mi][nf][2]); pk[3] = f2bf(acc[mi][nf][3]);
          size_t off = ((size_t)(bb * Hn + hh) * HSz + hs) * Tq + tt0;
          __builtin_memcpy(&vtout[off], &pk, 8);
        } else {
          u16* dst = (part == 0) ? qout : kout;
#pragma unroll
          for (int rr = 0; rr < 4; ++rr) {
            size_t off = ((size_t)(bb * Hn + hh) * Tq + (tt0 + rr)) * HSz + hs;
            dst[off] = f2bf(acc[mi][nf][rr]);
          }
        }
      }
    }
  } else {
#pragma unroll
    for (int mi = 0; mi < 8; ++mi) {
      const int trow = m0 + wm * 128 + mi * 16 + lg * 4;
#pragma unroll
      for (int nf = 0; nf < 4; ++nf) {
        const int d = n0 + wn * 64 + nf * 16 + lr;
        const float bv = bias[d];
#pragma unroll
        for (int rr = 0; rr < 4; ++rr)
          fout[(size_t)(trow + rr) * Cq + d] = acc[mi][nf][rr] + bv;
      }
    }
  }
}

// ---------------- flash attention (causal, balanced + double-buffered) ----------------
#define KVB 64
__global__ __launch_bounds__(256, 2)
void attn_fwd(const u16* __restrict__ qb, const u16* __restrict__ kb,
              const u16* __restrict__ vtb, u16* __restrict__ ob) {
  __shared__ u16 Ks[2 * KVB * HSz];   // 2 x 16KB, rows=kv (256B), swizzled
  __shared__ u16 Vs[2 * HSz * KVB];   // 2 x 16KB, rows=d (128B), swizzled
  __shared__ u16 Ps[4 * 32 * 32];     // 8KB, per-wave 32x32 chunk (swizzled)

  const int tid = threadIdx.x;
  const int w = tid >> 6, l = tid & 63;
  const int lr = l & 15, lg = l >> 4;
  const int bh = blockIdx.x, jj0 = blockIdx.y;
  const int b = bh >> 4, h = bh & 15;

  const u16* qp = qb + (size_t)bh * Tq * HSz;
  const u16* kp = kb + (size_t)bh * Tq * HSz;
  const u16* vp = vtb + (size_t)bh * HSz * Tq;

#pragma unroll 1
  for (int pass = 0; pass < 2; ++pass) {
    const int qt = pass ? (15 - jj0) : jj0;
    const int q0 = qt * 128;

    bf16x8 qf[2][4];
#pragma unroll
    for (int mi = 0; mi < 2; ++mi)
#pragma unroll
      for (int kk = 0; kk < 4; ++kk) {
        int row = q0 + w * 32 + mi * 16 + lr;
        qf[mi][kk] = ld_frag(qp + (size_t)row * HSz + kk * 32 + lg * 8);
      }

    const f32x4 fz = {0.f, 0.f, 0.f, 0.f};
    f32x4 o[2][8];
    float mrow[2][4], lrow[2][4];
#pragma unroll
    for (int mi = 0; mi < 2; ++mi) {
#pragma unroll
      for (int nj = 0; nj < 8; ++nj) o[mi][nj] = fz;
#pragma unroll
      for (int rr = 0; rr < 4; ++rr) { mrow[mi][rr] = -1e30f; lrow[mi][rr] = 0.f; }
    }

    const int nt = 2 * (qt + 1);

    auto stage = [&](int t, int buf) {
      const int kv0 = t * KVB;
      u16* Kb = &Ks[buf * (KVB * HSz)];
      u16* Vb = &Vs[buf * (HSz * KVB)];
#pragma unroll
      for (int i = 0; i < 4; ++i) {
        int c = w * 4 + i;
        {  // K chunk: 4 rows x 256B
          int r = c * 4 + lg;
          int cb = (lr * 16) ^ ((r & 7) << 4);
          glds16(&Kb[c * 512], (const char*)(kp + (size_t)(kv0 + r) * HSz) + cb);
        }
        {  // V chunk: 8 rows x 128B
          int r = c * 8 + (l >> 3);
          int cb = ((l & 7) * 16) ^ ((r & 7) << 4);
          glds16(&Vb[c * 512], (const char*)(vp + (size_t)r * Tq + kv0) + cb);
        }
      }
    };

    stage(0, 0);
#pragma unroll 1
    for (int t = 0; t < nt; ++t) {
      const int buf = t & 1;
      if (t + 1 < nt) {
        stage(t + 1, buf ^ 1);
        asm volatile("s_waitcnt vmcnt(8)\ns_barrier" ::: "memory");
      } else {
        asm volatile("s_waitcnt vmcnt(0)\ns_barrier" ::: "memory");
      }
      const u16* Ksb = &Ks[buf * (KVB * HSz)];
      const u16* Vsb = &Vs[buf * (HSz * KVB)];
      const int kv0 = t * KVB;

      f32x4 s[2][4];
#pragma unroll
      for (int mi = 0; mi < 2; ++mi)
#pragma unroll
        for (int nj = 0; nj < 4; ++nj) s[mi][nj] = fz;
#pragma unroll
      for (int kk = 0; kk < 4; ++kk) {
        bf16x8 kf[4];
#pragma unroll
        for (int nj = 0; nj < 4; ++nj) {
          int row = nj * 16 + lr;
          int cb = (kk * 64 + lg * 16) ^ ((row & 7) << 4);
          kf[nj] = ld_frag((const char*)Ksb + row * 256 + cb);
        }
        __builtin_amdgcn_s_setprio(1);
#pragma unroll
        for (int mi = 0; mi < 2; ++mi)
#pragma unroll
          for (int nj = 0; nj < 4; ++nj)
            s[mi][nj] = __builtin_amdgcn_mfma_f32_16x16x32_bf16(qf[mi][kk], kf[nj], s[mi][nj], 0, 0, 0);
        __builtin_amdgcn_s_setprio(0);
      }

      const bool diag = (t >= nt - 2);
      float corr[2][4];
      bool grew = false;
#pragma unroll
      for (int mi = 0; mi < 2; ++mi) {
#pragma unroll
        for (int rr = 0; rr < 4; ++rr) {
          const int qrow = q0 + w * 32 + mi * 16 + lg * 4 + rr;
          float pm = -1e30f;
#pragma unroll
          for (int nj = 0; nj < 4; ++nj) {
            float v = s[mi][nj][rr] * SCALE_QK;
            if (diag && (kv0 + nj * 16 + lr) > qrow) v = -1e30f;
            s[mi][nj][rr] = v;
            pm = fmaxf(pm, v);
          }
          pm = fmaxf(pm, __shfl_xor(pm, 1));
          pm = fmaxf(pm, __shfl_xor(pm, 2));
          pm = fmaxf(pm, __shfl_xor(pm, 4));
          pm = fmaxf(pm, __shfl_xor(pm, 8));
          float mo = mrow[mi][rr];
          float mn = fmaxf(mo, pm);
          corr[mi][rr] = __expf(mo - mn);
          grew |= (pm > mo);
          mrow[mi][rr] = mn;
          float rs = 0.f;
#pragma unroll
          for (int nj = 0; nj < 4; ++nj) {
            float p = __expf(s[mi][nj][rr] - mn);
            s[mi][nj][rr] = p;
            rs += p;
          }
          rs += __shfl_xor(rs, 1);
          rs += __shfl_xor(rs, 2);
          rs += __shfl_xor(rs, 4);
          rs += __shfl_xor(rs, 8);
          lrow[mi][rr] = lrow[mi][rr] * corr[mi][rr] + rs;
        }
      }
      if (__any(grew)) {
#pragma unroll
        for (int mi = 0; mi < 2; ++mi)
#pragma unroll
          for (int nj = 0; nj < 8; ++nj)
#pragma unroll
            for (int rr = 0; rr < 4; ++rr) o[mi][nj][rr] *= corr[mi][rr];
      }

      char* pw = (char*)Ps + w * 2048;
#pragma unroll
      for (int kk = 0; kk < 2; ++kk) {
#pragma unroll
        for (int mi = 0; mi < 2; ++mi)
#pragma unroll
          for (int jj = 0; jj < 2; ++jj) {
            int nj = kk * 2 + jj;
#pragma unroll
            for (int rr = 0; rr < 4; ++rr) {
              int prow = mi * 16 + lg * 4 + rr;
              int pcb = (jj * 16 + lr) * 2;
              *(u16*)(pw + ((prow * 64 + pcb) ^ ((prow & 7) << 4))) = f2bf(s[mi][nj][rr]);
            }
          }
        bf16x8 pa[2];
#pragma unroll
        for (int mi = 0; mi < 2; ++mi) {
          int prow = mi * 16 + lr;
          pa[mi] = ld_frag(pw + ((prow * 64 + lg * 16) ^ ((prow & 7) << 4)));
        }
        __builtin_amdgcn_s_setprio(1);
#pragma unroll
        for (int nj = 0; nj < 8; ++nj) {
          int vrow = nj * 16 + lr;
          int cb = (kk * 64 + lg * 16) ^ ((vrow & 7) << 4);
          bf16x8 vf = ld_frag((const char*)Vsb + vrow * 128 + cb);
#pragma unroll
          for (int mi = 0; mi < 2; ++mi)
            o[mi][nj] = __builtin_amdgcn_mfma_f32_16x16x32_bf16(pa[mi], vf, o[mi][nj], 0, 0, 0);
        }
        __builtin_amdgcn_s_setprio(0);
      }

      asm volatile("s_barrier" ::: "memory");
    }

#pragma unroll
    for (int mi = 0; mi < 2; ++mi)
#pragma unroll
      for (int rr = 0; rr < 4; ++rr) {
        int trow = q0 + w * 32 + mi * 16 + lg * 4 + rr;
        float inv = 1.f / lrow[mi][rr];
#pragma unroll
        for (int nj = 0; nj < 8; ++nj) {
          int d = nj * 16 + lr;
          ob[((size_t)b * Tq + trow) * Cq + h * HSz + d] = f2bf(o[mi][nj][rr] * inv);
        }
      }
  }
}

// ---------------- launch ----------------
extern "C" void kernel_launch(void* const* d_in, const int* in_sizes, int n_in,
                              void* d_out, int out_size, void* d_ws, size_t ws_size,
                              hipStream_t stream) {
  const float* x = (const float*)d_in[0];       // [4,2048,2048]
  const float* w_qkv = (const float*)d_in[1];   // [6144,2048]
  const float* w_proj = (const float*)d_in[2];  // [2048,2048]
  const float* b_proj = (const float*)d_in[3];  // [2048]
  float* out = (float*)d_out;

  char* ws = (char*)d_ws;
  u16* xb     = (u16*)(ws);                         // 32 MiB  x bf16 / later attn-out bf16
  u16* wqkvb  = (u16*)(ws + (size_t)33554432);      // 24 MiB
  u16* wprojb = (u16*)(ws + (size_t)58720256);      // 8 MiB
  u16* qbp    = (u16*)(ws + (size_t)67108864);      // 32 MiB [B,H,T,HS]
  u16* kbp    = (u16*)(ws + (size_t)100663296);     // 32 MiB [B,H,T,HS]
  u16* vtbp   = (u16*)(ws + (size_t)134217728);     // 32 MiB [B,H,HS,T]
  (void)in_sizes; (void)n_in; (void)out_size; (void)ws_size;

  cvt_bf16<<<16384, 256, 0, stream>>>(x, xb, 16777216);
  cvt_bf16<<<12288, 256, 0, stream>>>(w_qkv, wqkvb, 12582912);
  cvt_bf16<<<4096, 256, 0, stream>>>(w_proj, wprojb, 4194304);

  // QKV: M=8192, N=6144, K=2048  (grid 24x32 = 768 blocks)
  gemm256<0><<<dim3(24, 32), 512, 0, stream>>>(xb, wqkvb, 2048, qbp, kbp, vtbp, nullptr, nullptr);

  // attention (attn output overwrites xb; x no longer needed)
  attn_fwd<<<dim3(64, 8), 256, 0, stream>>>(qbp, kbp, vtbp, xb);

  // proj: M=8192, N=2048, K=2048, fp32 out + bias (grid 8x32 = 256 blocks)
  gemm256<1><<<dim3(8, 32), 512, 0, stream>>>(xb, wprojb, 2048, nullptr, nullptr, nullptr, out, b_proj);
}

// Round 7
// 465.942 us; speedup vs baseline: 1.6237x; 1.0088x over previous
//
#include <hip/hip_runtime.h>

// Problem dims (hardcoded)
#define Tq 2048
#define Cq 2048
#define Hn 16
#define HSz 128
#define Bq 4
#define SCALE_QK 0.08838834764831845f  // 1/sqrt(128)

typedef __bf16 bf16x8 __attribute__((ext_vector_type(8)));
typedef float f32x4 __attribute__((ext_vector_type(4)));
typedef unsigned short u16;
typedef u16 u16x4 __attribute__((ext_vector_type(4)));

__device__ __forceinline__ u16 f2bf(float f) {
  unsigned u = __builtin_bit_cast(unsigned, f);
  u += 0x7FFFu + ((u >> 16) & 1u);   // RNE
  return (u16)(u >> 16);
}

__device__ __forceinline__ bf16x8 ld_frag(const void* p) {
  bf16x8 v; __builtin_memcpy(&v, p, 16); return v;
}

__device__ __forceinline__ void glds16(void* lds, const void* g) {
  __builtin_amdgcn_global_load_lds(
      (const __attribute__((address_space(1))) void*)g,
      (__attribute__((address_space(3))) void*)lds, 16, 0, 0);
}

// ---------------- fp32 -> bf16 conversion ----------------
__global__ void cvt_bf16(const float* __restrict__ in, u16* __restrict__ out, int n) {
  int i = (blockIdx.x * 256 + threadIdx.x) * 4;
  if (i >= n) return;
  f32x4 v; __builtin_memcpy(&v, in + i, 16);
  u16x4 o;
  o[0] = f2bf(v[0]); o[1] = f2bf(v[1]); o[2] = f2bf(v[2]); o[3] = f2bf(v[3]);
  __builtin_memcpy(out + i, &o, 8);
}

// ---------------- 256x256 4-phase BT GEMM (T2+T3+T4+T5, XCD swizzle) ----------------
// C[m][n] = sum_k A[m][k] * Bm[n][k]. 512 threads = 8 waves (2M x 4N), BK=64,
// 2 K-tiles per iteration (slot0/slot1), 4 phases/iter, 32 MFMA per phase
// (two C-quadrants, reusing in-register B frags), uniform vmcnt(8) fence per
// phase (regions read in phase p are fenced in phase p-1, staged in p-3).
// Region WAR: every STAGE targets a region whose last ds_read was in a prior
// phase (reads retire before that phase's closing barrier).

#define LDA(s, mh) do { \
  _Pragma("unroll") for (int mi2_ = 0; mi2_ < 4; ++mi2_) \
  _Pragma("unroll") for (int kk_ = 0; kk_ < 2; ++kk_) { \
    const int row_ = (mh)*128 + wm*64 + mi2_*16 + lr; \
    af[mi2_*2+kk_] = ld_frag(AsB + (s)*32768 + row_*128 + ((kk_*64 + lg*16) ^ swz)); \
  } } while(0)

#define LDB(s, nh, BF) do { \
  _Pragma("unroll") for (int nf2_ = 0; nf2_ < 2; ++nf2_) \
  _Pragma("unroll") for (int kk_ = 0; kk_ < 2; ++kk_) { \
    const int row_ = (nh)*128 + wn*32 + nf2_*16 + lr; \
    BF[nf2_*2+kk_] = ld_frag(BsB + (s)*32768 + row_*128 + ((kk_*64 + lg*16) ^ swz)); \
  } } while(0)

#define QUAD(mh, nh, BF) do { \
  _Pragma("unroll") for (int mi2_ = 0; mi2_ < 4; ++mi2_) \
  _Pragma("unroll") for (int nf2_ = 0; nf2_ < 2; ++nf2_) \
  _Pragma("unroll") for (int kk_ = 0; kk_ < 2; ++kk_) \
    acc[(mh)*4+mi2_][(nh)*2+nf2_] = __builtin_amdgcn_mfma_f32_16x16x32_bf16( \
        af[mi2_*2+kk_], BF[nf2_*2+kk_], acc[(mh)*4+mi2_][(nh)*2+nf2_], 0, 0, 0); \
  } while(0)

#define STAGE_A(s, mh, k0) do { \
    u16* dst_ = Asu + (s)*16384 + (mh)*8192; \
    const u16* sp_ = A + (size_t)(m0 + (mh)*64 + arow0) * K + (k0) + srcE; \
    glds16(dst_ + w*512, sp_); \
    glds16(dst_ + (8+w)*512, sp_ + (size_t)128 * K); \
  } while(0)

#define STAGE_B(s, nh, k0) do { \
    u16* dst_ = Bsu + (s)*16384 + (nh)*8192; \
    glds16(dst_ + w*512,     Bm + (size_t)(n0 + (nh)*32 + brow0) * K + (k0) + srcE); \
    glds16(dst_ + (8+w)*512, Bm + (size_t)(n0 + (nh)*32 + brow1) * K + (k0) + srcE); \
  } while(0)

#define SYNC_MFMA(...) do { \
    asm volatile("s_barrier" ::: "memory"); \
    __builtin_amdgcn_s_setprio(1); \
    __VA_ARGS__; \
    __builtin_amdgcn_s_setprio(0); \
    asm volatile("s_barrier" ::: "memory"); \
  } while(0)

#define FENCE(n) asm volatile("s_waitcnt vmcnt(" #n ")" ::: "memory")

template <int EPI>
__global__ __launch_bounds__(512)
void gemm256(const u16* __restrict__ A, const u16* __restrict__ Bm, int K,
             u16* __restrict__ qout, u16* __restrict__ kout, u16* __restrict__ vtout,
             float* __restrict__ fout, const float* __restrict__ bias) {
  __shared__ u16 As2[2 * 256 * 64];   // 64 KB
  __shared__ u16 Bs2[2 * 256 * 64];   // 64 KB
  const int tid = threadIdx.x;
  const int w = tid >> 6, l = tid & 63;
  const int wm = w >> 2, wn = w & 3;
  const int lr = l & 15, lg = l >> 4;
  const int swz = (lr & 7) << 4;

  // bijective XCD swizzle (nwg % 8 == 0 for all our grids)
  const int nwg = gridDim.x * gridDim.y;
  int ow = blockIdx.y * gridDim.x + blockIdx.x;
  ow = (ow & 7) * (nwg >> 3) + (ow >> 3);
  const int bx = ow % gridDim.x, by = ow / gridDim.x;
  const int m0 = by * 256, n0 = bx * 256;

  // staging precompute (chunk c = issue*8 + w; lane covers row c*8+(l>>3), bytes (l&7)*16)
  const int r0 = w * 8 + (l >> 3);                  // issue-0 region row (0..63)
  const int arow0 = r0;                             // A: issue-1 row = arow0+128 (same inner)
  const int brow0 = (r0 >> 5) * 64 + (r0 & 31);
  const int brow1 = (((r0 + 64) >> 5) & 3) * 64 + (r0 & 31);
  const int srcE = ((l & 7) ^ (l >> 3)) << 3;       // pre-swizzled source element col

  u16* Asu = As2; u16* Bsu = Bs2;
  const char* AsB = (const char*)As2;
  const char* BsB = (const char*)Bs2;

  f32x4 acc[8][4];
  const f32x4 fz = {0.f, 0.f, 0.f, 0.f};
#pragma unroll
  for (int i = 0; i < 8; ++i)
#pragma unroll
    for (int j = 0; j < 4; ++j) acc[i][j] = fz;

  bf16x8 af[8], bf0[4], bf1[4];

  // prologue: stage pair-0 regions in steady-state order (14 loads/wave)
  STAGE_A(0, 0, 0);  STAGE_B(0, 0, 0);  STAGE_B(0, 1, 0);   // read at P1
  STAGE_A(0, 1, 0);                                          // read at P2
  STAGE_A(1, 0, 64); STAGE_B(1, 0, 64); STAGE_B(1, 1, 64);   // read at P3
  FENCE(8);                                                  // P1 regions landed
  asm volatile("s_barrier" ::: "memory");

  const int NP = K >> 7;   // pairs of K-tiles
#pragma unroll 1
  for (int t = 0; t < NP - 1; ++t) {
    const int kt = t << 7;
    const int kA = kt + 128;   // pair t+1 k-base

    // P1: reads slot0 A-mh0 + B both; stage A11(t); fence covers P2's A01(t)
    LDA(0, 0); LDB(0, 0, bf0); LDB(0, 1, bf1);
    STAGE_A(1, 1, kt + 64);
    FENCE(8);
    SYNC_MFMA(QUAD(0, 0, bf0); QUAD(0, 1, bf1));
    // P2: reads slot0 A-mh1; stage A00',B00',B01'; fence covers P3 regions
    LDA(0, 1);
    STAGE_A(0, 0, kA); STAGE_B(0, 0, kA); STAGE_B(0, 1, kA);
    FENCE(8);
    SYNC_MFMA(QUAD(1, 1, bf1); QUAD(1, 0, bf0));
    // P3: reads slot1 A-mh0 + B both; stage A01'; fence covers P4's A11(t)
    LDA(1, 0); LDB(1, 0, bf0); LDB(1, 1, bf1);
    STAGE_A(0, 1, kA);
    FENCE(8);
    SYNC_MFMA(QUAD(0, 0, bf0); QUAD(0, 1, bf1));
    // P4: reads slot1 A-mh1; stage A10',B10',B11'; fence covers next-P1 regions
    LDA(1, 1);
    STAGE_A(1, 0, kA + 64); STAGE_B(1, 0, kA + 64); STAGE_B(1, 1, kA + 64);
    FENCE(8);
    SYNC_MFMA(QUAD(1, 1, bf1); QUAD(1, 0, bf0));
  }

  // peeled last pair (no next-pair staging; drain fences)
  {
    const int kt = (NP - 1) << 7;
    LDA(0, 0); LDB(0, 0, bf0); LDB(0, 1, bf1);
    STAGE_A(1, 1, kt + 64);
    FENCE(8);
    SYNC_MFMA(QUAD(0, 0, bf0); QUAD(0, 1, bf1));
    LDA(0, 1);
    FENCE(2);
    SYNC_MFMA(QUAD(1, 1, bf1); QUAD(1, 0, bf0));
    LDA(1, 0); LDB(1, 0, bf0); LDB(1, 1, bf1);
    FENCE(0);
    SYNC_MFMA(QUAD(0, 0, bf0); QUAD(0, 1, bf1));
    LDA(1, 1);
    SYNC_MFMA(QUAD(1, 1, bf1); QUAD(1, 0, bf0));
  }

  // epilogue. C/D layout: col = lr, row = lg*4 + rr
  if constexpr (EPI == 0) {
#pragma unroll
    for (int mi = 0; mi < 8; ++mi) {
      const int trow = m0 + wm * 128 + mi * 16 + lg * 4;  // +rr
      const int bb = trow >> 11, tt0 = trow & 2047;
#pragma unroll
      for (int nf = 0; nf < 4; ++nf) {
        const int d = n0 + wn * 64 + nf * 16 + lr;  // 0..6143
        const int part = d >> 11;
        const int dd = d & 2047;
        const int hh = dd >> 7, hs = dd & 127;
        if (part == 2) {
          u16x4 pk;
          pk[0] = f2bf(acc[mi][nf][0]); pk[1] = f2bf(acc[mi][nf][1]);
          pk[2] = f2bf(acc[mi][nf][2]); pk[3] = f2bf(acc[mi][nf][3]);
          size_t off = ((size_t)(bb * Hn + hh) * HSz + hs) * Tq + tt0;
          __builtin_memcpy(&vtout[off], &pk, 8);
        } else {
          u16* dst = (part == 0) ? qout : kout;
#pragma unroll
          for (int rr = 0; rr < 4; ++rr) {
            size_t off = ((size_t)(bb * Hn + hh) * Tq + (tt0 + rr)) * HSz + hs;
            dst[off] = f2bf(acc[mi][nf][rr]);
          }
        }
      }
    }
  } else {
#pragma unroll
    for (int mi = 0; mi < 8; ++mi) {
      const int trow = m0 + wm * 128 + mi * 16 + lg * 4;
#pragma unroll
      for (int nf = 0; nf < 4; ++nf) {
        const int d = n0 + wn * 64 + nf * 16 + lr;
        const float bv = bias[d];
#pragma unroll
        for (int rr = 0; rr < 4; ++rr)
          fout[(size_t)(trow + rr) * Cq + d] = acc[mi][nf][rr] + bv;
      }
    }
  }
}

// ---------------- flash attention (causal, balanced + double-buffered) ----------------
#define KVB 64
__global__ __launch_bounds__(256, 2)
void attn_fwd(const u16* __restrict__ qb, const u16* __restrict__ kb,
              const u16* __restrict__ vtb, u16* __restrict__ ob) {
  __shared__ u16 Ks[2 * KVB * HSz];   // 2 x 16KB, rows=kv (256B), swizzled
  __shared__ u16 Vs[2 * HSz * KVB];   // 2 x 16KB, rows=d (128B), swizzled
  __shared__ u16 Ps[4 * 32 * 32];     // 8KB, per-wave 32x32 chunk (swizzled)

  const int tid = threadIdx.x;
  const int w = tid >> 6, l = tid & 63;
  const int lr = l & 15, lg = l >> 4;
  const int bh = blockIdx.x, jj0 = blockIdx.y;
  const int b = bh >> 4, h = bh & 15;

  const u16* qp = qb + (size_t)bh * Tq * HSz;
  const u16* kp = kb + (size_t)bh * Tq * HSz;
  const u16* vp = vtb + (size_t)bh * HSz * Tq;

#pragma unroll 1
  for (int pass = 0; pass < 2; ++pass) {
    const int qt = pass ? (15 - jj0) : jj0;
    const int q0 = qt * 128;

    bf16x8 qf[2][4];
#pragma unroll
    for (int mi = 0; mi < 2; ++mi)
#pragma unroll
      for (int kk = 0; kk < 4; ++kk) {
        int row = q0 + w * 32 + mi * 16 + lr;
        qf[mi][kk] = ld_frag(qp + (size_t)row * HSz + kk * 32 + lg * 8);
      }

    const f32x4 fz = {0.f, 0.f, 0.f, 0.f};
    f32x4 o[2][8];
    float mrow[2][4], lrow[2][4];
#pragma unroll
    for (int mi = 0; mi < 2; ++mi) {
#pragma unroll
      for (int nj = 0; nj < 8; ++nj) o[mi][nj] = fz;
#pragma unroll
      for (int rr = 0; rr < 4; ++rr) { mrow[mi][rr] = -1e30f; lrow[mi][rr] = 0.f; }
    }

    const int nt = 2 * (qt + 1);

    auto stage = [&](int t, int buf) {
      const int kv0 = t * KVB;
      u16* Kb = &Ks[buf * (KVB * HSz)];
      u16* Vb = &Vs[buf * (HSz * KVB)];
#pragma unroll
      for (int i = 0; i < 4; ++i) {
        int c = w * 4 + i;
        {  // K chunk: 4 rows x 256B
          int r = c * 4 + lg;
          int cb = (lr * 16) ^ ((r & 7) << 4);
          glds16(&Kb[c * 512], (const char*)(kp + (size_t)(kv0 + r) * HSz) + cb);
        }
        {  // V chunk: 8 rows x 128B
          int r = c * 8 + (l >> 3);
          int cb = ((l & 7) * 16) ^ ((r & 7) << 4);
          glds16(&Vb[c * 512], (const char*)(vp + (size_t)r * Tq + kv0) + cb);
        }
      }
    };

    stage(0, 0);
#pragma unroll 1
    for (int t = 0; t < nt; ++t) {
      const int buf = t & 1;
      if (t + 1 < nt) {
        stage(t + 1, buf ^ 1);
        asm volatile("s_waitcnt vmcnt(8)\ns_barrier" ::: "memory");
      } else {
        asm volatile("s_waitcnt vmcnt(0)\ns_barrier" ::: "memory");
      }
      const u16* Ksb = &Ks[buf * (KVB * HSz)];
      const u16* Vsb = &Vs[buf * (HSz * KVB)];
      const int kv0 = t * KVB;

      f32x4 s[2][4];
#pragma unroll
      for (int mi = 0; mi < 2; ++mi)
#pragma unroll
        for (int nj = 0; nj < 4; ++nj) s[mi][nj] = fz;
#pragma unroll
      for (int kk = 0; kk < 4; ++kk) {
        bf16x8 kf[4];
#pragma unroll
        for (int nj = 0; nj < 4; ++nj) {
          int row = nj * 16 + lr;
          int cb = (kk * 64 + lg * 16) ^ ((row & 7) << 4);
          kf[nj] = ld_frag((const char*)Ksb + row * 256 + cb);
        }
        __builtin_amdgcn_s_setprio(1);
#pragma unroll
        for (int mi = 0; mi < 2; ++mi)
#pragma unroll
          for (int nj = 0; nj < 4; ++nj)
            s[mi][nj] = __builtin_amdgcn_mfma_f32_16x16x32_bf16(qf[mi][kk], kf[nj], s[mi][nj], 0, 0, 0);
        __builtin_amdgcn_s_setprio(0);
      }

      const bool diag = (t >= nt - 2);
      float corr[2][4];
      bool grew = false;
#pragma unroll
      for (int mi = 0; mi < 2; ++mi) {
#pragma unroll
        for (int rr = 0; rr < 4; ++rr) {
          const int qrow = q0 + w * 32 + mi * 16 + lg * 4 + rr;
          float pm = -1e30f;
#pragma unroll
          for (int nj = 0; nj < 4; ++nj) {
            float v = s[mi][nj][rr] * SCALE_QK;
            if (diag && (kv0 + nj * 16 + lr) > qrow) v = -1e30f;
            s[mi][nj][rr] = v;
            pm = fmaxf(pm, v);
          }
          pm = fmaxf(pm, __shfl_xor(pm, 1));
          pm = fmaxf(pm, __shfl_xor(pm, 2));
          pm = fmaxf(pm, __shfl_xor(pm, 4));
          pm = fmaxf(pm, __shfl_xor(pm, 8));
          float mo = mrow[mi][rr];
          float mn = fmaxf(mo, pm);
          corr[mi][rr] = __expf(mo - mn);
          grew |= (pm > mo);
          mrow[mi][rr] = mn;
          float rs = 0.f;
#pragma unroll
          for (int nj = 0; nj < 4; ++nj) {
            float p = __expf(s[mi][nj][rr] - mn);
            s[mi][nj][rr] = p;
            rs += p;
          }
          rs += __shfl_xor(rs, 1);
          rs += __shfl_xor(rs, 2);
          rs += __shfl_xor(rs, 4);
          rs += __shfl_xor(rs, 8);
          lrow[mi][rr] = lrow[mi][rr] * corr[mi][rr] + rs;
        }
      }
      if (__any(grew)) {
#pragma unroll
        for (int mi = 0; mi < 2; ++mi)
#pragma unroll
          for (int nj = 0; nj < 8; ++nj)
#pragma unroll
            for (int rr = 0; rr < 4; ++rr) o[mi][nj][rr] *= corr[mi][rr];
      }

      char* pw = (char*)Ps + w * 2048;
#pragma unroll
      for (int kk = 0; kk < 2; ++kk) {
#pragma unroll
        for (int mi = 0; mi < 2; ++mi)
#pragma unroll
          for (int jj = 0; jj < 2; ++jj) {
            int nj = kk * 2 + jj;
#pragma unroll
            for (int rr = 0; rr < 4; ++rr) {
              int prow = mi * 16 + lg * 4 + rr;
              int pcb = (jj * 16 + lr) * 2;
              *(u16*)(pw + ((prow * 64 + pcb) ^ ((prow & 7) << 4))) = f2bf(s[mi][nj][rr]);
            }
          }
        bf16x8 pa[2];
#pragma unroll
        for (int mi = 0; mi < 2; ++mi) {
          int prow = mi * 16 + lr;
          pa[mi] = ld_frag(pw + ((prow * 64 + lg * 16) ^ ((prow & 7) << 4)));
        }
        __builtin_amdgcn_s_setprio(1);
#pragma unroll
        for (int nj = 0; nj < 8; ++nj) {
          int vrow = nj * 16 + lr;
          int cb = (kk * 64 + lg * 16) ^ ((vrow & 7) << 4);
          bf16x8 vf = ld_frag((const char*)Vsb + vrow * 128 + cb);
#pragma unroll
          for (int mi = 0; mi < 2; ++mi)
            o[mi][nj] = __builtin_amdgcn_mfma_f32_16x16x32_bf16(pa[mi], vf, o[mi][nj], 0, 0, 0);
        }
        __builtin_amdgcn_s_setprio(0);
      }

      asm volatile("s_barrier" ::: "memory");
    }

#pragma unroll
    for (int mi = 0; mi < 2; ++mi)
#pragma unroll
      for (int rr = 0; rr < 4; ++rr) {
        int trow = q0 + w * 32 + mi * 16 + lg * 4 + rr;
        float inv = 1.f / lrow[mi][rr];
#pragma unroll
        for (int nj = 0; nj < 8; ++nj) {
          int d = nj * 16 + lr;
          ob[((size_t)b * Tq + trow) * Cq + h * HSz + d] = f2bf(o[mi][nj][rr] * inv);
        }
      }
  }
}

// ---------------- launch ----------------
extern "C" void kernel_launch(void* const* d_in, const int* in_sizes, int n_in,
                              void* d_out, int out_size, void* d_ws, size_t ws_size,
                              hipStream_t stream) {
  const float* x = (const float*)d_in[0];       // [4,2048,2048]
  const float* w_qkv = (const float*)d_in[1];   // [6144,2048]
  const float* w_proj = (const float*)d_in[2];  // [2048,2048]
  const float* b_proj = (const float*)d_in[3];  // [2048]
  float* out = (float*)d_out;

  char* ws = (char*)d_ws;
  u16* xb     = (u16*)(ws);                         // 32 MiB  x bf16 / later attn-out bf16
  u16* wqkvb  = (u16*)(ws + (size_t)33554432);      // 24 MiB
  u16* wprojb = (u16*)(ws + (size_t)58720256);      // 8 MiB
  u16* qbp    = (u16*)(ws + (size_t)67108864);      // 32 MiB [B,H,T,HS]
  u16* kbp    = (u16*)(ws + (size_t)100663296);     // 32 MiB [B,H,T,HS]
  u16* vtbp   = (u16*)(ws + (size_t)134217728);     // 32 MiB [B,H,HS,T]
  (void)in_sizes; (void)n_in; (void)out_size; (void)ws_size;

  cvt_bf16<<<16384, 256, 0, stream>>>(x, xb, 16777216);
  cvt_bf16<<<12288, 256, 0, stream>>>(w_qkv, wqkvb, 12582912);
  cvt_bf16<<<4096, 256, 0, stream>>>(w_proj, wprojb, 4194304);

  // QKV: M=8192, N=6144, K=2048  (grid 24x32 = 768 blocks)
  gemm256<0><<<dim3(24, 32), 512, 0, stream>>>(xb, wqkvb, 2048, qbp, kbp, vtbp, nullptr, nullptr);

  // attention (attn output overwrites xb; x no longer needed)
  attn_fwd<<<dim3(64, 8), 256, 0, stream>>>(qbp, kbp, vtbp, xb);

  // proj: M=8192, N=2048, K=2048, fp32 out + bias (grid 8x32 = 256 blocks)
  gemm256<1><<<dim3(8, 32), 512, 0, stream>>>(xb, wprojb, 2048, nullptr, nullptr, nullptr, out, b_proj);
}